// Round 3
// baseline (218.700 us; speedup 1.0000x reference)
//
#include <hip/hip_runtime.h>
#include <hip/hip_bf16.h>
#include <stdint.h>

typedef __attribute__((ext_vector_type(8))) short short8;
typedef __attribute__((ext_vector_type(4))) float f32x4;

static __device__ __forceinline__ unsigned short f2bf(float f) {
  union { float f; unsigned u; } v; v.f = f;
  return (unsigned short)((v.u + 0x7fffu + ((v.u >> 16) & 1u)) >> 16);
}
static __device__ __forceinline__ float bf2f(unsigned short h) {
  union { unsigned u; float f; } v; v.u = ((unsigned)h) << 16;
  return v.f;
}

// async global->LDS, 16B per lane (guide §5; LDS dest = wave-uniform base + lane*16)
#define GLL16(gp, lp) __builtin_amdgcn_global_load_lds(                        \
    (__attribute__((address_space(1))) void*)(uintptr_t)(gp),                  \
    (__attribute__((address_space(3))) void*)(lp), 16, 0, 0)

// element-index XOR swizzle for 64-elem (128B) bf16 rows: spreads the
// 128B-stride column reads across 8 bank-granules (T2; involution).
#define SWZ(r, e) ((e) ^ (((r) & 7) << 3))

// ---------------- cast f32 -> bf16, 4 elems/thread ----------------
__global__ void cast_f32_bf16(const float* __restrict__ in,
                              unsigned short* __restrict__ out, int n4) {
  int i = blockIdx.x * 256 + threadIdx.x;
  if (i >= n4) return;
  const float4 v = reinterpret_cast<const float4*>(in)[i];
  ushort4 o;
  o.x = f2bf(v.x); o.y = f2bf(v.y); o.z = f2bf(v.z); o.w = f2bf(v.w);
  reinterpret_cast<ushort4*>(out)[i] = o;
}

// ---------------- NT GEMM: C[M][N] = A[M][K] * B[N][K]^T (bf16 in, f32 acc) --
// 128x128 tile, BK=32, 256 threads (2x2 waves, each 64x64 = 4x4 16x16 frags)
template <int OUT_BF16>
__global__ __launch_bounds__(256) void gemm_nt(
    const unsigned short* __restrict__ A, const unsigned short* __restrict__ B,
    void* __restrict__ Cout, int M, int N, int K) {
  __shared__ unsigned short As[128 * 32];
  __shared__ unsigned short Bs[128 * 32];
  const int tid = threadIdx.x;
  const int lane = tid & 63;
  const int w = tid >> 6;
  const int wr = w >> 1, wc = w & 1;
  const int l15 = lane & 15, lg = lane >> 4;
  const size_t bm = (size_t)blockIdx.x * 128;
  const size_t bn = (size_t)blockIdx.y * 128;
  const unsigned short* Ab = A + bm * K;
  const unsigned short* Bb = B + bn * K;
  f32x4 acc[4][4];
#pragma unroll
  for (int m = 0; m < 4; ++m)
#pragma unroll
    for (int n = 0; n < 4; ++n) acc[m][n] = (f32x4){0.f, 0.f, 0.f, 0.f};

  for (int k0 = 0; k0 < K; k0 += 32) {
    __syncthreads();
#pragma unroll
    for (int p = 0; p < 2; ++p) {
      const int flat = p * 256 + tid;     // 0..511
      const int row = flat >> 2;          // 128 rows, 4 chunks/row
      const int c8 = (flat & 3) << 3;
      GLL16(Ab + (size_t)row * K + k0 + c8, As + flat * 8);
      GLL16(Bb + (size_t)row * K + k0 + c8, Bs + flat * 8);
    }
    __syncthreads();
    short8 af[4], bf[4];
#pragma unroll
    for (int m = 0; m < 4; ++m)
      af[m] = *reinterpret_cast<const short8*>(As + ((wr * 64 + m * 16 + l15) * 32 + lg * 8));
#pragma unroll
    for (int n = 0; n < 4; ++n)
      bf[n] = *reinterpret_cast<const short8*>(Bs + ((wc * 64 + n * 16 + l15) * 32 + lg * 8));
#pragma unroll
    for (int m = 0; m < 4; ++m)
#pragma unroll
      for (int n = 0; n < 4; ++n)
        acc[m][n] = __builtin_amdgcn_mfma_f32_16x16x32_bf16(af[m], bf[n], acc[m][n], 0, 0, 0);
  }
  const size_t row0 = bm + wr * 64 + lg * 4;
  const size_t col0 = bn + wc * 64 + l15;
#pragma unroll
  for (int m = 0; m < 4; ++m)
#pragma unroll
    for (int n = 0; n < 4; ++n)
#pragma unroll
      for (int r = 0; r < 4; ++r) {
        const size_t row = row0 + m * 16 + r;
        const size_t col = col0 + n * 16;
        if (OUT_BF16)
          ((unsigned short*)Cout)[row * N + col] = f2bf(acc[m][n][r]);
        else
          ((float*)Cout)[row * N + col] = acc[m][n][r];
      }
}

// ---------------- RoPE on q,k; angles = h * 10000^(-jj/32) ------------------
// qkv rows m=b*2048+t, cols: [0,1024)=q [1024,2048)=k. Writes (b,h,t,d) bf16.
// Q is pre-scaled by 1/sqrt(D)*log2(e) so attn scores are exp2-ready (saves
// 16 VALU mults per s-tile per wave in attn).
__global__ void rope_qk(const unsigned short* __restrict__ qkvb,
                        unsigned short* __restrict__ qb,
                        unsigned short* __restrict__ kb) {
  const int idx = blockIdx.x * 256 + threadIdx.x;  // 4096*1024 total
  const int m = idx >> 10;
  const int r = idx & 1023;
  const int sec = r >> 9;  // 0=q, 1=k
  const int j = r & 511;
  const int h = j >> 5;
  const int jj = j & 31;
  const float freq = __expf(-(float)jj * (9.210340371976184f / 32.0f));  // ln(1e4)
  float s, c;
  __sincosf((float)h * freq, &s, &c);
  const unsigned pr = *reinterpret_cast<const unsigned*>(
      qkvb + (size_t)m * 3072 + sec * 1024 + h * 64 + 2 * jj);
  const float x0 = bf2f((unsigned short)(pr & 0xffffu));
  const float x1 = bf2f((unsigned short)(pr >> 16));
  const float scl = (sec == 0) ? (0.125f * 1.44269504089f) : 1.0f;
  const float o0 = (x0 * c - x1 * s) * scl;
  const float o1 = (x0 * s + x1 * c) * scl;
  const unsigned out = (unsigned)f2bf(o0) | ((unsigned)f2bf(o1) << 16);
  const int b = m >> 11, t = m & 2047;
  unsigned short* dst = (sec == 0) ? qb : kb;
  *reinterpret_cast<unsigned*>(dst + (((size_t)(b * 16 + h) * 2048 + t) * 64 + 2 * jj)) = out;
}

// ---------------- V transpose: qkv v-section -> vt[(b,h,d,s)] bf16 ----------
__global__ void v_transpose(const unsigned short* __restrict__ qkvb,
                            unsigned short* __restrict__ vt) {
  __shared__ unsigned short tile[64][66];  // +2 pad: conflict-free column reads
  const int tid = threadIdx.x;
  const int bh = blockIdx.x;
  const int b = bh >> 4, h = bh & 15;
  const int s0 = blockIdx.y * 64;
#pragma unroll
  for (int p = 0; p < 2; ++p) {
    const int f = p * 256 + tid;
    const int sr = f >> 3;
    const int c8 = (f & 7) << 3;
    const short8 v = *reinterpret_cast<const short8*>(
        qkvb + (size_t)(b * 2048 + s0 + sr) * 3072 + 2048 + h * 64 + c8);
#pragma unroll
    for (int e = 0; e < 8; ++e) tile[sr][c8 + e] = (unsigned short)v[e];
  }
  __syncthreads();
#pragma unroll
  for (int p = 0; p < 2; ++p) {
    const int f = p * 256 + tid;
    const int dr = f >> 3;
    const int s8 = (f & 7) << 3;
    short8 o;
#pragma unroll
    for (int e = 0; e < 8; ++e) o[e] = (short)tile[s8 + e][dr];
    *reinterpret_cast<short8*>(vt + ((size_t)bh * 64 + dr) * 2048 + s0 + s8) = o;
  }
}

// ---------------- flash attention, causal, per-wave online softmax ----------
// grid (32, B*H), qt = 31-bx (heavy q-tiles dispatch first -> tail packing).
// K/V double-buffered + prefetch-before-compute; T2 swizzle; T13 defer-max;
// T5 setprio around MFMA clusters. Q pre-scaled (log2 domain) in rope_qk.
__global__ __launch_bounds__(256) void attn_kernel(
    const unsigned short* __restrict__ qb, const unsigned short* __restrict__ kb,
    const unsigned short* __restrict__ vt, unsigned short* __restrict__ ctx) {
  __shared__ unsigned short Ks[2][64 * 64];  // [s][d], swizzled
  __shared__ unsigned short Vs[2][64 * 64];  // [d][s], swizzled
  __shared__ unsigned short Ps[4][16 * 64];  // per-wave P [q][s], swizzled
  const int tid = threadIdx.x;
  const int lane = tid & 63;
  const int w = tid >> 6;
  const int l15 = lane & 15, lg = lane >> 4;
  const int bh = blockIdx.y;
  const int b = bh >> 4, h = bh & 15;
  unsigned short* Pw = &Ps[w][0];

  const int qt = 31 - (int)blockIdx.x;  // descending work order
  const int qw = qt * 64 + w * 16;
  const unsigned short* Qp = qb + ((size_t)bh * 2048 + qw) * 64;
  const short8 qf0 = *reinterpret_cast<const short8*>(Qp + (size_t)l15 * 64 + lg * 8);
  const short8 qf1 = *reinterpret_cast<const short8*>(Qp + (size_t)l15 * 64 + 32 + lg * 8);
  float mrun[4], lrun[4];
  f32x4 o[4];
#pragma unroll
  for (int r = 0; r < 4; ++r) { mrun[r] = -1e30f; lrun[r] = 0.f; }
#pragma unroll
  for (int dt = 0; dt < 4; ++dt) o[dt] = (f32x4){0.f, 0.f, 0.f, 0.f};
  const int nt = qt + 1;

  // prologue stage into buf 0 (pre-swizzled global source, rule #21)
#pragma unroll
  for (int p = 0; p < 2; ++p) {
    const int f = p * 256 + tid;
    const int row = f >> 3;
    const int gc8 = SWZ(row, (f & 7) << 3);
    GLL16(kb + ((size_t)bh * 2048 + row) * 64 + gc8, &Ks[0][f * 8]);
    GLL16(vt + ((size_t)bh * 64 + row) * 2048 + gc8, &Vs[0][f * 8]);
  }
  __syncthreads();

  int cur = 0;
#pragma unroll 1
  for (int it = 0; it < nt; ++it) {
    const int s0 = it * 64;
    // issue next tile's loads BEFORE compute - latency hides under compute
    if (it + 1 < nt) {
      const int s1 = s0 + 64;
#pragma unroll
      for (int p = 0; p < 2; ++p) {
        const int f = p * 256 + tid;
        const int row = f >> 3;
        const int gc8 = SWZ(row, (f & 7) << 3);
        GLL16(kb + ((size_t)bh * 2048 + s1 + row) * 64 + gc8, &Ks[cur ^ 1][f * 8]);
        GLL16(vt + ((size_t)bh * 64 + row) * 2048 + s1 + gc8, &Vs[cur ^ 1][f * 8]);
      }
    }
    const unsigned short* Kc = &Ks[cur][0];
    const unsigned short* Vc = &Vs[cur][0];
    // QK^T: S[16q][64s] (already in log2-scaled domain via Q prescale)
    f32x4 sc[4];
    __builtin_amdgcn_s_setprio(1);
#pragma unroll
    for (int st = 0; st < 4; ++st) {
      const int kr = st * 16 + l15;
      const short8 kf0 = *reinterpret_cast<const short8*>(Kc + kr * 64 + SWZ(kr, lg * 8));
      const short8 kf1 = *reinterpret_cast<const short8*>(Kc + kr * 64 + SWZ(kr, 32 + lg * 8));
      f32x4 z = (f32x4){0.f, 0.f, 0.f, 0.f};
      z = __builtin_amdgcn_mfma_f32_16x16x32_bf16(qf0, kf0, z, 0, 0, 0);
      z = __builtin_amdgcn_mfma_f32_16x16x32_bf16(qf1, kf1, z, 0, 0, 0);
      sc[st] = z;
    }
    __builtin_amdgcn_s_setprio(0);
    // causal mask (diagonal tile only) + row max
    float tmax[4] = {-1e30f, -1e30f, -1e30f, -1e30f};
    if (s0 + 63 > qw) {  // wave-uniform branch
#pragma unroll
      for (int st = 0; st < 4; ++st)
#pragma unroll
        for (int r = 0; r < 4; ++r) {
          float v = sc[st][r];
          if (s0 + st * 16 + l15 > qw + lg * 4 + r) v = -1e30f;
          sc[st][r] = v;
          tmax[r] = fmaxf(tmax[r], v);
        }
    } else {
#pragma unroll
      for (int st = 0; st < 4; ++st)
#pragma unroll
        for (int r = 0; r < 4; ++r) tmax[r] = fmaxf(tmax[r], sc[st][r]);
    }
#pragma unroll
    for (int r = 0; r < 4; ++r) {
      tmax[r] = fmaxf(tmax[r], __shfl_xor(tmax[r], 1));
      tmax[r] = fmaxf(tmax[r], __shfl_xor(tmax[r], 2));
      tmax[r] = fmaxf(tmax[r], __shfl_xor(tmax[r], 4));
      tmax[r] = fmaxf(tmax[r], __shfl_xor(tmax[r], 8));
    }
    // T13 defer-max: only rescale when some row's max grew past mrun+8
    bool need = false;
#pragma unroll
    for (int r = 0; r < 4; ++r) need = need || (tmax[r] > mrun[r] + 8.f);
    if (__any((int)need)) {
#pragma unroll
      for (int r = 0; r < 4; ++r) {
        const float mn = fmaxf(mrun[r], tmax[r]);
        const float c = exp2f(mrun[r] - mn);
        mrun[r] = mn;
        lrun[r] *= c;
        o[0][r] *= c; o[1][r] *= c; o[2][r] *= c; o[3][r] *= c;
      }
    }
    float psum[4] = {0.f, 0.f, 0.f, 0.f};
#pragma unroll
    for (int st = 0; st < 4; ++st)
#pragma unroll
      for (int r = 0; r < 4; ++r) {
        const float p = exp2f(sc[st][r] - mrun[r]);  // bounded by 2^8
        psum[r] += p;
        const int q = lg * 4 + r;
        Pw[q * 64 + SWZ(q, st * 16 + l15)] = f2bf(p);  // C-frag -> [q][s]
      }
#pragma unroll
    for (int r = 0; r < 4; ++r) {
      psum[r] += __shfl_xor(psum[r], 1);
      psum[r] += __shfl_xor(psum[r], 2);
      psum[r] += __shfl_xor(psum[r], 4);
      psum[r] += __shfl_xor(psum[r], 8);
      lrun[r] += psum[r];
    }
    // PV: O[16q][64d] += P[16q][64s] * V[64s][64d]
    __builtin_amdgcn_s_setprio(1);
#pragma unroll
    for (int sc2 = 0; sc2 < 2; ++sc2) {
      const short8 pf =
          *reinterpret_cast<const short8*>(Pw + l15 * 64 + SWZ(l15, sc2 * 32 + lg * 8));
#pragma unroll
      for (int dt = 0; dt < 4; ++dt) {
        const int vr = dt * 16 + l15;
        const short8 vf =
            *reinterpret_cast<const short8*>(Vc + vr * 64 + SWZ(vr, sc2 * 32 + lg * 8));
        o[dt] = __builtin_amdgcn_mfma_f32_16x16x32_bf16(pf, vf, o[dt], 0, 0, 0);
      }
    }
    __builtin_amdgcn_s_setprio(0);
    __syncthreads();  // implicit vmcnt(0): next tile staged AND buf[cur] free
    cur ^= 1;
  }
  float inv[4];
#pragma unroll
  for (int r = 0; r < 4; ++r) inv[r] = __builtin_amdgcn_rcpf(lrun[r]);
#pragma unroll
  for (int dt = 0; dt < 4; ++dt)
#pragma unroll
    for (int r = 0; r < 4; ++r) {
      const int t = qw + lg * 4 + r;
      ctx[(size_t)(b * 2048 + t) * 1024 + h * 64 + dt * 16 + l15] = f2bf(o[dt][r] * inv[r]);
    }
}

// ---------------- launch ----------------------------------------------------
extern "C" void kernel_launch(void* const* d_in, const int* in_sizes, int n_in,
                              void* d_out, int out_size, void* d_ws, size_t ws_size,
                              hipStream_t stream) {
  const float* x = (const float*)d_in[0];
  const float* w_qkv = (const float*)d_in[1];
  const float* w_out = (const float*)d_in[2];
  // cache_k/cache_v/start_pos unused: start_pos=0, cache starts zero and is not returned.
  char* ws = (char*)d_ws;
  unsigned short* xb    = (unsigned short*)(ws);                       // 8 MiB
  unsigned short* wqkvb = (unsigned short*)(ws + (8ull  << 20));       // 6 MiB
  unsigned short* woutb = (unsigned short*)(ws + (14ull << 20));       // 2 MiB
  unsigned short* qkvb  = (unsigned short*)(ws + (16ull << 20));       // 24 MiB
  unsigned short* q_buf = (unsigned short*)(ws + (40ull << 20));       // 8 MiB
  unsigned short* k_buf = (unsigned short*)(ws + (48ull << 20));       // 8 MiB
  unsigned short* vt    = (unsigned short*)(ws + (56ull << 20));       // 8 MiB
  unsigned short* ctxb  = (unsigned short*)(ws + (64ull << 20));       // 8 MiB (total 72)

  cast_f32_bf16<<<4096, 256, 0, stream>>>(x, xb, 4194304 / 4);
  cast_f32_bf16<<<3072, 256, 0, stream>>>(w_qkv, wqkvb, 3145728 / 4);
  cast_f32_bf16<<<1024, 256, 0, stream>>>(w_out, woutb, 1048576 / 4);
  gemm_nt<1><<<dim3(32, 24), 256, 0, stream>>>(xb, wqkvb, qkvb, 4096, 3072, 1024);
  rope_qk<<<16384, 256, 0, stream>>>(qkvb, q_buf, k_buf);
  v_transpose<<<dim3(32, 32), 256, 0, stream>>>(qkvb, vt);
  attn_kernel<<<dim3(32, 32), 256, 0, stream>>>(q_buf, k_buf, vt, ctxb);
  gemm_nt<0><<<dim3(32, 8), 256, 0, stream>>>(ctxb, woutb, d_out, 4096, 1024, 1024);
}

// Round 4
// 146.424 us; speedup vs baseline: 1.4936x; 1.4936x over previous
//
#include <hip/hip_runtime.h>
#include <hip/hip_bf16.h>
#include <stdint.h>

typedef __attribute__((ext_vector_type(8))) short short8;
typedef __attribute__((ext_vector_type(4))) float f32x4;

static __device__ __forceinline__ unsigned short f2bf(float f) {
  union { float f; unsigned u; } v; v.f = f;
  return (unsigned short)((v.u + 0x7fffu + ((v.u >> 16) & 1u)) >> 16);
}
static __device__ __forceinline__ float bf2f(unsigned short h) {
  union { unsigned u; float f; } v; v.u = ((unsigned)h) << 16;
  return v.f;
}
// packed f32x2 -> bf16x2 (RNE), gfx950 (no builtin; T12 recipe)
static __device__ __forceinline__ unsigned cvt_pk_bf16(float lo, float hi) {
  unsigned r;
  asm("v_cvt_pk_bf16_f32 %0, %1, %2" : "=v"(r) : "v"(lo), "v"(hi));
  return r;
}

// async global->LDS, 16B per lane (guide §5; LDS dest = wave-uniform base + lane*16)
#define GLL16(gp, lp) __builtin_amdgcn_global_load_lds(                        \
    (__attribute__((address_space(1))) void*)(uintptr_t)(gp),                  \
    (__attribute__((address_space(3))) void*)(lp), 16, 0, 0)

// element-index XOR swizzle for 64-elem (128B) bf16 rows: spreads the
// 128B-stride column reads across 8 bank-granules (T2; involution).
#define SWZ(r, e) ((e) ^ (((r) & 7) << 3))

// ---------------- cast f32 -> bf16, 4 elems/thread ----------------
__global__ void cast_f32_bf16(const float* __restrict__ in,
                              unsigned short* __restrict__ out, int n4) {
  int i = blockIdx.x * 256 + threadIdx.x;
  if (i >= n4) return;
  const float4 v = reinterpret_cast<const float4*>(in)[i];
  ushort4 o;
  o.x = f2bf(v.x); o.y = f2bf(v.y); o.z = f2bf(v.z); o.w = f2bf(v.w);
  reinterpret_cast<ushort4*>(out)[i] = o;
}

// ---------------- NT GEMM: C[M][N] = A[M][K] * B[N][K]^T (bf16 in, f32 acc) --
// 128x128 tile, BK=32, 256 threads (2x2 waves, each 64x64 = 4x4 16x16 frags)
template <int OUT_BF16>
__global__ __launch_bounds__(256) void gemm_nt(
    const unsigned short* __restrict__ A, const unsigned short* __restrict__ B,
    void* __restrict__ Cout, int M, int N, int K) {
  __shared__ unsigned short As[128 * 32];
  __shared__ unsigned short Bs[128 * 32];
  const int tid = threadIdx.x;
  const int lane = tid & 63;
  const int w = tid >> 6;
  const int wr = w >> 1, wc = w & 1;
  const int l15 = lane & 15, lg = lane >> 4;
  const size_t bm = (size_t)blockIdx.x * 128;
  const size_t bn = (size_t)blockIdx.y * 128;
  const unsigned short* Ab = A + bm * K;
  const unsigned short* Bb = B + bn * K;
  f32x4 acc[4][4];
#pragma unroll
  for (int m = 0; m < 4; ++m)
#pragma unroll
    for (int n = 0; n < 4; ++n) acc[m][n] = (f32x4){0.f, 0.f, 0.f, 0.f};

  for (int k0 = 0; k0 < K; k0 += 32) {
    __syncthreads();
#pragma unroll
    for (int p = 0; p < 2; ++p) {
      const int flat = p * 256 + tid;     // 0..511
      const int row = flat >> 2;          // 128 rows, 4 chunks/row
      const int c8 = (flat & 3) << 3;
      GLL16(Ab + (size_t)row * K + k0 + c8, As + flat * 8);
      GLL16(Bb + (size_t)row * K + k0 + c8, Bs + flat * 8);
    }
    __syncthreads();
    short8 af[4], bf[4];
#pragma unroll
    for (int m = 0; m < 4; ++m)
      af[m] = *reinterpret_cast<const short8*>(As + ((wr * 64 + m * 16 + l15) * 32 + lg * 8));
#pragma unroll
    for (int n = 0; n < 4; ++n)
      bf[n] = *reinterpret_cast<const short8*>(Bs + ((wc * 64 + n * 16 + l15) * 32 + lg * 8));
#pragma unroll
    for (int m = 0; m < 4; ++m)
#pragma unroll
      for (int n = 0; n < 4; ++n)
        acc[m][n] = __builtin_amdgcn_mfma_f32_16x16x32_bf16(af[m], bf[n], acc[m][n], 0, 0, 0);
  }
  const size_t row0 = bm + wr * 64 + lg * 4;
  const size_t col0 = bn + wc * 64 + l15;
#pragma unroll
  for (int m = 0; m < 4; ++m)
#pragma unroll
    for (int n = 0; n < 4; ++n)
#pragma unroll
      for (int r = 0; r < 4; ++r) {
        const size_t row = row0 + m * 16 + r;
        const size_t col = col0 + n * 16;
        if (OUT_BF16)
          ((unsigned short*)Cout)[row * N + col] = f2bf(acc[m][n][r]);
        else
          ((float*)Cout)[row * N + col] = acc[m][n][r];
      }
}

// ---------------- RoPE on q,k; angles = h * 10000^(-jj/32) ------------------
// qkv rows m=b*2048+t, cols: [0,1024)=q [1024,2048)=k. Writes (b,h,t,d) bf16.
// Q is pre-scaled by 1/sqrt(D)*log2(e) so attn scores are exp2-ready.
__global__ void rope_qk(const unsigned short* __restrict__ qkvb,
                        unsigned short* __restrict__ qb,
                        unsigned short* __restrict__ kb) {
  const int idx = blockIdx.x * 256 + threadIdx.x;  // 4096*1024 total
  const int m = idx >> 10;
  const int r = idx & 1023;
  const int sec = r >> 9;  // 0=q, 1=k
  const int j = r & 511;
  const int h = j >> 5;
  const int jj = j & 31;
  const float freq = __expf(-(float)jj * (9.210340371976184f / 32.0f));  // ln(1e4)
  float s, c;
  __sincosf((float)h * freq, &s, &c);
  const unsigned pr = *reinterpret_cast<const unsigned*>(
      qkvb + (size_t)m * 3072 + sec * 1024 + h * 64 + 2 * jj);
  const float x0 = bf2f((unsigned short)(pr & 0xffffu));
  const float x1 = bf2f((unsigned short)(pr >> 16));
  const float scl = (sec == 0) ? (0.125f * 1.44269504089f) : 1.0f;
  const float o0 = (x0 * c - x1 * s) * scl;
  const float o1 = (x0 * s + x1 * c) * scl;
  const unsigned out = (unsigned)f2bf(o0) | ((unsigned)f2bf(o1) << 16);
  const int b = m >> 11, t = m & 2047;
  unsigned short* dst = (sec == 0) ? qb : kb;
  *reinterpret_cast<unsigned*>(dst + (((size_t)(b * 16 + h) * 2048 + t) * 64 + 2 * jj)) = out;
}

// ---------------- V transpose: qkv v-section -> vt[(b,h,d,s)] bf16 ----------
__global__ void v_transpose(const unsigned short* __restrict__ qkvb,
                            unsigned short* __restrict__ vt) {
  __shared__ unsigned short tile[64][66];  // +2 pad: conflict-free column reads
  const int tid = threadIdx.x;
  const int bh = blockIdx.x;
  const int b = bh >> 4, h = bh & 15;
  const int s0 = blockIdx.y * 64;
#pragma unroll
  for (int p = 0; p < 2; ++p) {
    const int f = p * 256 + tid;
    const int sr = f >> 3;
    const int c8 = (f & 7) << 3;
    const short8 v = *reinterpret_cast<const short8*>(
        qkvb + (size_t)(b * 2048 + s0 + sr) * 3072 + 2048 + h * 64 + c8);
#pragma unroll
    for (int e = 0; e < 8; ++e) tile[sr][c8 + e] = (unsigned short)v[e];
  }
  __syncthreads();
#pragma unroll
  for (int p = 0; p < 2; ++p) {
    const int f = p * 256 + tid;
    const int dr = f >> 3;
    const int s8 = (f & 7) << 3;
    short8 o;
#pragma unroll
    for (int e = 0; e < 8; ++e) o[e] = (short)tile[s8 + e][dr];
    *reinterpret_cast<short8*>(vt + ((size_t)bh * 64 + dr) * 2048 + s0 + s8) = o;
  }
}

// ---------------- flash attention, causal, swapped-QK^T softmax -------------
// grid (16, B*H). Block pairs q-tiles (x, 31-x): uniform 33 s-tiles/block
// (R2 balanced grid). Swapped QK^T (mfma(K,Q)): score col=q(l15), row=s -
// softmax row-state is lane-local (1 reg), P->bf16 via cvt_pk + ds_write_b64.
__global__ __launch_bounds__(256) void attn_kernel(
    const unsigned short* __restrict__ qb, const unsigned short* __restrict__ kb,
    const unsigned short* __restrict__ vt, unsigned short* __restrict__ ctx) {
  __shared__ unsigned short Ks[2][64 * 64];  // [s][d], swizzled
  __shared__ unsigned short Vs[2][64 * 64];  // [d][s], swizzled
  __shared__ unsigned short Ps[4][16 * 64];  // per-wave P [q][s], swizzled
  const int tid = threadIdx.x;
  const int lane = tid & 63;
  const int w = tid >> 6;
  const int l15 = lane & 15, lg = lane >> 4;
  const int bh = blockIdx.y;
  const int b = bh >> 4, h = bh & 15;
  unsigned short* Pw = &Ps[w][0];

  // staging base pointers (strength-reduced; advance by const stride per tile)
  const unsigned short* kg[2];
  const unsigned short* vg[2];
#pragma unroll
  for (int p = 0; p < 2; ++p) {
    const int f = p * 256 + tid;
    const int row = f >> 3;
    const int gc8 = SWZ(row, (f & 7) << 3);
    kg[p] = kb + ((size_t)bh * 2048 + row) * 64 + gc8;  // +64*64 per s-tile
    vg[p] = vt + ((size_t)bh * 64 + row) * 2048 + gc8;  // +64 per s-tile
  }

#pragma unroll 1
  for (int mem = 0; mem < 2; ++mem) {
    const int qt = mem ? (31 - (int)blockIdx.x) : (int)blockIdx.x;
    const int qw = qt * 64 + w * 16;
    const unsigned short* Qp = qb + ((size_t)bh * 2048 + qw) * 64;
    const short8 qf0 = *reinterpret_cast<const short8*>(Qp + (size_t)l15 * 64 + lg * 8);
    const short8 qf1 = *reinterpret_cast<const short8*>(Qp + (size_t)l15 * 64 + 32 + lg * 8);
    // per-lane softmax state for q-row (qw + l15), replicated across lg
    float mrun = -1e30f, lrun = 0.f;
    f32x4 o[4];
#pragma unroll
    for (int dt = 0; dt < 4; ++dt) o[dt] = (f32x4){0.f, 0.f, 0.f, 0.f};
    const int nt = qt + 1;

    // prologue stage into buf 0
#pragma unroll
    for (int p = 0; p < 2; ++p) {
      const int f = p * 256 + tid;
      GLL16(kg[p], &Ks[0][f * 8]);
      GLL16(vg[p], &Vs[0][f * 8]);
    }
    __syncthreads();

    int cur = 0;
#pragma unroll 1
    for (int it = 0; it < nt; ++it) {
      const int s0 = it * 64;
      // issue next tile's loads BEFORE compute
      if (it + 1 < nt) {
#pragma unroll
        for (int p = 0; p < 2; ++p) {
          const int f = p * 256 + tid;
          GLL16(kg[p] + (size_t)(it + 1) * 64 * 64, &Ks[cur ^ 1][f * 8]);
          GLL16(vg[p] + (size_t)(it + 1) * 64, &Vs[cur ^ 1][f * 8]);
        }
      }
      const unsigned short* Kc = &Ks[cur][0];
      const unsigned short* Vc = &Vs[cur][0];
      // swapped QK^T: sc[st] col(l15)=q, row(lg*4+r)=s_local=st*16+lg*4+r
      f32x4 sc[4];
      __builtin_amdgcn_s_setprio(1);
#pragma unroll
      for (int st = 0; st < 4; ++st) {
        const int kr = st * 16 + l15;
        const short8 kf0 = *reinterpret_cast<const short8*>(Kc + kr * 64 + SWZ(kr, lg * 8));
        const short8 kf1 = *reinterpret_cast<const short8*>(Kc + kr * 64 + SWZ(kr, 32 + lg * 8));
        f32x4 z = (f32x4){0.f, 0.f, 0.f, 0.f};
        z = __builtin_amdgcn_mfma_f32_16x16x32_bf16(kf0, qf0, z, 0, 0, 0);
        z = __builtin_amdgcn_mfma_f32_16x16x32_bf16(kf1, qf1, z, 0, 0, 0);
        sc[st] = z;
      }
      __builtin_amdgcn_s_setprio(0);
      // causal mask (diagonal tiles only): s = s0+st*16+lg*4+r, q = qw+l15
      if (s0 + 63 > qw) {
        const int sbase = s0 + lg * 4 - qw - l15;  // mask iff sbase+st*16+r > 0
#pragma unroll
        for (int st = 0; st < 4; ++st)
#pragma unroll
          for (int r = 0; r < 4; ++r)
            if (sbase + st * 16 + r > 0) sc[st][r] = -1e30f;
      }
      // in-lane max over 16 s-values, then reduce across lg (xor 16, 32)
      float tmax = sc[0][0];
#pragma unroll
      for (int st = 0; st < 4; ++st)
#pragma unroll
        for (int r = 0; r < 4; ++r) tmax = fmaxf(tmax, sc[st][r]);
      tmax = fmaxf(tmax, __shfl_xor(tmax, 16));
      tmax = fmaxf(tmax, __shfl_xor(tmax, 32));
      // T13 defer-max
      if (__any(tmax > mrun + 8.f)) {
        const float mn = fmaxf(mrun, tmax);
        const float c = exp2f(mrun - mn);
        mrun = mn;
        lrun *= c;
        // O rows are q = lg*4+r -> fetch c from lane (lg*4+r)
#pragma unroll
        for (int r = 0; r < 4; ++r) {
          const float cq = __shfl(c, lg * 4 + r);
          o[0][r] *= cq; o[1][r] *= cq; o[2][r] *= cq; o[3][r] *= cq;
        }
      }
      // P = exp2(sc - mrun); pack 4 consecutive s as 2x cvt_pk -> ds_write_b64
      float psum = 0.f;
#pragma unroll
      for (int st = 0; st < 4; ++st) {
        const float p0 = exp2f(sc[st][0] - mrun);
        const float p1 = exp2f(sc[st][1] - mrun);
        const float p2 = exp2f(sc[st][2] - mrun);
        const float p3 = exp2f(sc[st][3] - mrun);
        psum += (p0 + p1) + (p2 + p3);
        const unsigned lo = cvt_pk_bf16(p0, p1);
        const unsigned hi = cvt_pk_bf16(p2, p3);
        const int off = l15 * 64 + SWZ(l15, st * 16 + lg * 4);
        *reinterpret_cast<uint2*>(Pw + off) = make_uint2(lo, hi);
      }
      psum += __shfl_xor(psum, 16);
      psum += __shfl_xor(psum, 32);
      lrun += psum;
      // PV: O[16q][64d] += P[16q][64s] * V[64s][64d]  (unchanged layout)
      __builtin_amdgcn_s_setprio(1);
#pragma unroll
      for (int sc2 = 0; sc2 < 2; ++sc2) {
        const short8 pf =
            *reinterpret_cast<const short8*>(Pw + l15 * 64 + SWZ(l15, sc2 * 32 + lg * 8));
#pragma unroll
        for (int dt = 0; dt < 4; ++dt) {
          const int vr = dt * 16 + l15;
          const short8 vf =
              *reinterpret_cast<const short8*>(Vc + vr * 64 + SWZ(vr, sc2 * 32 + lg * 8));
          o[dt] = __builtin_amdgcn_mfma_f32_16x16x32_bf16(pf, vf, o[dt], 0, 0, 0);
        }
      }
      __builtin_amdgcn_s_setprio(0);
      __syncthreads();  // implicit vmcnt(0): next tile staged AND buf[cur] free
      cur ^= 1;
    }
    const float linv = __builtin_amdgcn_rcpf(lrun);
#pragma unroll
    for (int r = 0; r < 4; ++r) {
      const float invq = __shfl(linv, lg * 4 + r);
      const int t = qw + lg * 4 + r;
#pragma unroll
      for (int dt = 0; dt < 4; ++dt)
        ctx[(size_t)(b * 2048 + t) * 1024 + h * 64 + dt * 16 + l15] = f2bf(o[dt][r] * invq);
    }
  }
}

// ---------------- launch ----------------------------------------------------
extern "C" void kernel_launch(void* const* d_in, const int* in_sizes, int n_in,
                              void* d_out, int out_size, void* d_ws, size_t ws_size,
                              hipStream_t stream) {
  const float* x = (const float*)d_in[0];
  const float* w_qkv = (const float*)d_in[1];
  const float* w_out = (const float*)d_in[2];
  // cache_k/cache_v/start_pos unused: start_pos=0, cache starts zero and is not returned.
  char* ws = (char*)d_ws;
  unsigned short* xb    = (unsigned short*)(ws);                       // 8 MiB
  unsigned short* wqkvb = (unsigned short*)(ws + (8ull  << 20));       // 6 MiB
  unsigned short* woutb = (unsigned short*)(ws + (14ull << 20));       // 2 MiB
  unsigned short* qkvb  = (unsigned short*)(ws + (16ull << 20));       // 24 MiB
  unsigned short* q_buf = (unsigned short*)(ws + (40ull << 20));       // 8 MiB
  unsigned short* k_buf = (unsigned short*)(ws + (48ull << 20));       // 8 MiB
  unsigned short* vt    = (unsigned short*)(ws + (56ull << 20));       // 8 MiB
  unsigned short* ctxb  = (unsigned short*)(ws + (64ull << 20));       // 8 MiB (total 72)

  cast_f32_bf16<<<4096, 256, 0, stream>>>(x, xb, 4194304 / 4);
  cast_f32_bf16<<<3072, 256, 0, stream>>>(w_qkv, wqkvb, 3145728 / 4);
  cast_f32_bf16<<<1024, 256, 0, stream>>>(w_out, woutb, 1048576 / 4);
  gemm_nt<1><<<dim3(32, 24), 256, 0, stream>>>(xb, wqkvb, qkvb, 4096, 3072, 1024);
  rope_qk<<<16384, 256, 0, stream>>>(qkvb, q_buf, k_buf);
  v_transpose<<<dim3(32, 32), 256, 0, stream>>>(qkvb, vt);
  attn_kernel<<<dim3(16, 32), 256, 0, stream>>>(q_buf, k_buf, vt, ctxb);
  gemm_nt<0><<<dim3(32, 8), 256, 0, stream>>>(ctxb, woutb, d_out, 4096, 1024, 1024);
}

// Round 5
// 142.192 us; speedup vs baseline: 1.5381x; 1.0298x over previous
//
#include <hip/hip_runtime.h>
#include <hip/hip_bf16.h>
#include <stdint.h>

typedef __attribute__((ext_vector_type(8))) short short8;
typedef __attribute__((ext_vector_type(4))) float f32x4;

static __device__ __forceinline__ unsigned short f2bf(float f) {
  union { float f; unsigned u; } v; v.f = f;
  return (unsigned short)((v.u + 0x7fffu + ((v.u >> 16) & 1u)) >> 16);
}
static __device__ __forceinline__ float bf2f(unsigned short h) {
  union { unsigned u; float f; } v; v.u = ((unsigned)h) << 16;
  return v.f;
}
// packed f32x2 -> bf16x2 (RNE), gfx950 (no builtin; T12 recipe)
static __device__ __forceinline__ unsigned cvt_pk_bf16(float lo, float hi) {
  unsigned r;
  asm("v_cvt_pk_bf16_f32 %0, %1, %2" : "=v"(r) : "v"(lo), "v"(hi));
  return r;
}

// async global->LDS, 16B per lane (guide §5; LDS dest = wave-uniform base + lane*16)
#define GLL16(gp, lp) __builtin_amdgcn_global_load_lds(                        \
    (__attribute__((address_space(1))) void*)(uintptr_t)(gp),                  \
    (__attribute__((address_space(3))) void*)(lp), 16, 0, 0)

// element-index XOR swizzle for 64-elem (128B) bf16 rows: spreads the
// 128B-stride column reads across 8 bank-granules (T2; involution).
#define SWZ(r, e) ((e) ^ (((r) & 7) << 3))

// ---------------- cast f32 -> bf16, 4 elems/thread ----------------
__global__ void cast_f32_bf16(const float* __restrict__ in,
                              unsigned short* __restrict__ out, int n4) {
  int i = blockIdx.x * 256 + threadIdx.x;
  if (i >= n4) return;
  const float4 v = reinterpret_cast<const float4*>(in)[i];
  ushort4 o;
  o.x = f2bf(v.x); o.y = f2bf(v.y); o.z = f2bf(v.z); o.w = f2bf(v.w);
  reinterpret_cast<ushort4*>(out)[i] = o;
}

// ---------------- NT GEMM: C[M][N] = A[M][K] * B[N][K]^T (bf16 in, f32 acc) --
// 128x128 tile, BK=32, 256 threads (2x2 waves, each 64x64 = 4x4 16x16 frags)
template <int OUT_BF16>
__global__ __launch_bounds__(256) void gemm_nt(
    const unsigned short* __restrict__ A, const unsigned short* __restrict__ B,
    void* __restrict__ Cout, int M, int N, int K) {
  __shared__ unsigned short As[128 * 32];
  __shared__ unsigned short Bs[128 * 32];
  const int tid = threadIdx.x;
  const int lane = tid & 63;
  const int w = tid >> 6;
  const int wr = w >> 1, wc = w & 1;
  const int l15 = lane & 15, lg = lane >> 4;
  const size_t bm = (size_t)blockIdx.x * 128;
  const size_t bn = (size_t)blockIdx.y * 128;
  const unsigned short* Ab = A + bm * K;
  const unsigned short* Bb = B + bn * K;
  f32x4 acc[4][4];
#pragma unroll
  for (int m = 0; m < 4; ++m)
#pragma unroll
    for (int n = 0; n < 4; ++n) acc[m][n] = (f32x4){0.f, 0.f, 0.f, 0.f};

  for (int k0 = 0; k0 < K; k0 += 32) {
    __syncthreads();
#pragma unroll
    for (int p = 0; p < 2; ++p) {
      const int flat = p * 256 + tid;     // 0..511
      const int row = flat >> 2;          // 128 rows, 4 chunks/row
      const int c8 = (flat & 3) << 3;
      GLL16(Ab + (size_t)row * K + k0 + c8, As + flat * 8);
      GLL16(Bb + (size_t)row * K + k0 + c8, Bs + flat * 8);
    }
    __syncthreads();
    short8 af[4], bf[4];
#pragma unroll
    for (int m = 0; m < 4; ++m)
      af[m] = *reinterpret_cast<const short8*>(As + ((wr * 64 + m * 16 + l15) * 32 + lg * 8));
#pragma unroll
    for (int n = 0; n < 4; ++n)
      bf[n] = *reinterpret_cast<const short8*>(Bs + ((wc * 64 + n * 16 + l15) * 32 + lg * 8));
#pragma unroll
    for (int m = 0; m < 4; ++m)
#pragma unroll
      for (int n = 0; n < 4; ++n)
        acc[m][n] = __builtin_amdgcn_mfma_f32_16x16x32_bf16(af[m], bf[n], acc[m][n], 0, 0, 0);
  }
  const size_t row0 = bm + wr * 64 + lg * 4;
  const size_t col0 = bn + wc * 64 + l15;
#pragma unroll
  for (int m = 0; m < 4; ++m)
#pragma unroll
    for (int n = 0; n < 4; ++n)
#pragma unroll
      for (int r = 0; r < 4; ++r) {
        const size_t row = row0 + m * 16 + r;
        const size_t col = col0 + n * 16;
        if (OUT_BF16)
          ((unsigned short*)Cout)[row * N + col] = f2bf(acc[m][n][r]);
        else
          ((float*)Cout)[row * N + col] = acc[m][n][r];
      }
}

// ---------------- RoPE on q,k; angles = h * 10000^(-jj/32) ------------------
// qkv rows m=b*2048+t, cols: [0,1024)=q [1024,2048)=k. Writes (b,h,t,d) bf16.
// Q is pre-scaled by 1/sqrt(D)*log2(e) so attn scores are exp2-ready.
__global__ void rope_qk(const unsigned short* __restrict__ qkvb,
                        unsigned short* __restrict__ qb,
                        unsigned short* __restrict__ kb) {
  const int idx = blockIdx.x * 256 + threadIdx.x;  // 4096*1024 total
  const int m = idx >> 10;
  const int r = idx & 1023;
  const int sec = r >> 9;  // 0=q, 1=k
  const int j = r & 511;
  const int h = j >> 5;
  const int jj = j & 31;
  const float freq = __expf(-(float)jj * (9.210340371976184f / 32.0f));  // ln(1e4)
  float s, c;
  __sincosf((float)h * freq, &s, &c);
  const unsigned pr = *reinterpret_cast<const unsigned*>(
      qkvb + (size_t)m * 3072 + sec * 1024 + h * 64 + 2 * jj);
  const float x0 = bf2f((unsigned short)(pr & 0xffffu));
  const float x1 = bf2f((unsigned short)(pr >> 16));
  const float scl = (sec == 0) ? (0.125f * 1.44269504089f) : 1.0f;
  const float o0 = (x0 * c - x1 * s) * scl;
  const float o1 = (x0 * s + x1 * c) * scl;
  const unsigned out = (unsigned)f2bf(o0) | ((unsigned)f2bf(o1) << 16);
  const int b = m >> 11, t = m & 2047;
  unsigned short* dst = (sec == 0) ? qb : kb;
  *reinterpret_cast<unsigned*>(dst + (((size_t)(b * 16 + h) * 2048 + t) * 64 + 2 * jj)) = out;
}

// ---------------- V transpose: qkv v-section -> vt[(b,h,d,s)] bf16 ----------
__global__ void v_transpose(const unsigned short* __restrict__ qkvb,
                            unsigned short* __restrict__ vt) {
  __shared__ unsigned short tile[64][66];  // +2 pad: conflict-free column reads
  const int tid = threadIdx.x;
  const int bh = blockIdx.x;
  const int b = bh >> 4, h = bh & 15;
  const int s0 = blockIdx.y * 64;
#pragma unroll
  for (int p = 0; p < 2; ++p) {
    const int f = p * 256 + tid;
    const int sr = f >> 3;
    const int c8 = (f & 7) << 3;
    const short8 v = *reinterpret_cast<const short8*>(
        qkvb + (size_t)(b * 2048 + s0 + sr) * 3072 + 2048 + h * 64 + c8);
#pragma unroll
    for (int e = 0; e < 8; ++e) tile[sr][c8 + e] = (unsigned short)v[e];
  }
  __syncthreads();
#pragma unroll
  for (int p = 0; p < 2; ++p) {
    const int f = p * 256 + tid;
    const int dr = f >> 3;
    const int s8 = (f & 7) << 3;
    short8 o;
#pragma unroll
    for (int e = 0; e < 8; ++e) o[e] = (short)tile[s8 + e][dr];
    *reinterpret_cast<short8*>(vt + ((size_t)bh * 64 + dr) * 2048 + s0 + s8) = o;
  }
}

// ---------------- flash attention, causal, s-split x2 + partials ------------
// grid (32, B*H): px = x>>1 pairs q-tiles (px, 31-px); sx = x&1 selects the
// lower/upper half of each q-tile's s-range -> uniform ~16.5 tile-units/block,
// 1024 blocks = 4/CU (occupancy lever; R3 lesson: balance AND block count).
// Emits unnormalized partials (O bf16, m/l f32); attn_combine merges.
__global__ __launch_bounds__(256) void attn_kernel(
    const unsigned short* __restrict__ qb, const unsigned short* __restrict__ kb,
    const unsigned short* __restrict__ vt, unsigned short* __restrict__ partO,
    float2* __restrict__ partML) {
  __shared__ unsigned short Ks[2][64 * 64];  // [s][d], swizzled
  __shared__ unsigned short Vs[2][64 * 64];  // [d][s], swizzled
  __shared__ unsigned short Ps[4][16 * 64];  // per-wave P [q][s], swizzled
  const int tid = threadIdx.x;
  const int lane = tid & 63;
  const int w = tid >> 6;
  const int l15 = lane & 15, lg = lane >> 4;
  const int sx = blockIdx.x & 1, px = blockIdx.x >> 1;
  const int bh = blockIdx.y;
  unsigned short* Pw = &Ps[w][0];

  // staging base pointers (strength-reduced; advance by const stride per tile)
  const unsigned short* kg[2];
  const unsigned short* vg[2];
#pragma unroll
  for (int p = 0; p < 2; ++p) {
    const int f = p * 256 + tid;
    const int row = f >> 3;
    const int gc8 = SWZ(row, (f & 7) << 3);
    kg[p] = kb + ((size_t)bh * 2048 + row) * 64 + gc8;  // +64*64 per s-tile
    vg[p] = vt + ((size_t)bh * 64 + row) * 2048 + gc8;  // +64 per s-tile
  }

  int cur = 0;
#pragma unroll 1
  for (int mem = 0; mem < 2; ++mem) {
    const int qt = mem ? (31 - px) : px;
    const int nt = qt + 1;
    const int mid = (nt + 1) >> 1;
    const int sb = sx ? mid : 0;       // s-tile range [sb, se)
    const int se = sx ? nt : mid;
    const int nh = se - sb;
    const int qw = qt * 64 + w * 16;
    const unsigned short* Qp = qb + ((size_t)bh * 2048 + qw) * 64;
    const short8 qf0 = *reinterpret_cast<const short8*>(Qp + (size_t)l15 * 64 + lg * 8);
    const short8 qf1 = *reinterpret_cast<const short8*>(Qp + (size_t)l15 * 64 + 32 + lg * 8);
    float mrun = -1e30f, lrun = 0.f;  // per-lane state for q-row qw+l15
    f32x4 o[4];
#pragma unroll
    for (int dt = 0; dt < 4; ++dt) o[dt] = (f32x4){0.f, 0.f, 0.f, 0.f};

    if (nh > 0) {  // block-uniform
      // prologue stage tile sb into buf[cur]
#pragma unroll
      for (int p = 0; p < 2; ++p) {
        const int f = p * 256 + tid;
        GLL16(kg[p] + (size_t)sb * 64 * 64, &Ks[cur][f * 8]);
        GLL16(vg[p] + (size_t)sb * 64, &Vs[cur][f * 8]);
      }
      __syncthreads();

#pragma unroll 1
      for (int it = 0; it < nh; ++it) {
        const int ti = sb + it;
        const int s0 = ti * 64;
        // issue next tile's loads BEFORE compute
        if (it + 1 < nh) {
#pragma unroll
          for (int p = 0; p < 2; ++p) {
            const int f = p * 256 + tid;
            GLL16(kg[p] + (size_t)(ti + 1) * 64 * 64, &Ks[cur ^ 1][f * 8]);
            GLL16(vg[p] + (size_t)(ti + 1) * 64, &Vs[cur ^ 1][f * 8]);
          }
        }
        const unsigned short* Kc = &Ks[cur][0];
        const unsigned short* Vc = &Vs[cur][0];
        // swapped QK^T: sc[st] col(l15)=q, row(lg*4+r)=s_local=st*16+lg*4+r
        f32x4 sc[4];
        __builtin_amdgcn_s_setprio(1);
#pragma unroll
        for (int st = 0; st < 4; ++st) {
          const int kr = st * 16 + l15;
          const short8 kf0 = *reinterpret_cast<const short8*>(Kc + kr * 64 + SWZ(kr, lg * 8));
          const short8 kf1 = *reinterpret_cast<const short8*>(Kc + kr * 64 + SWZ(kr, 32 + lg * 8));
          f32x4 z = (f32x4){0.f, 0.f, 0.f, 0.f};
          z = __builtin_amdgcn_mfma_f32_16x16x32_bf16(kf0, qf0, z, 0, 0, 0);
          z = __builtin_amdgcn_mfma_f32_16x16x32_bf16(kf1, qf1, z, 0, 0, 0);
          sc[st] = z;
        }
        __builtin_amdgcn_s_setprio(0);
        // causal mask (diagonal tiles only): s = s0+st*16+lg*4+r, q = qw+l15
        if (s0 + 63 > qw) {
          const int sbase = s0 + lg * 4 - qw - l15;  // mask iff sbase+st*16+r > 0
#pragma unroll
          for (int st = 0; st < 4; ++st)
#pragma unroll
            for (int r = 0; r < 4; ++r)
              if (sbase + st * 16 + r > 0) sc[st][r] = -1e30f;
        }
        // in-lane max over 16 s-values, then reduce across lg (xor 16, 32)
        float tmax = sc[0][0];
#pragma unroll
        for (int st = 0; st < 4; ++st)
#pragma unroll
          for (int r = 0; r < 4; ++r) tmax = fmaxf(tmax, sc[st][r]);
        tmax = fmaxf(tmax, __shfl_xor(tmax, 16));
        tmax = fmaxf(tmax, __shfl_xor(tmax, 32));
        // T13 defer-max
        if (__any(tmax > mrun + 8.f)) {
          const float mn = fmaxf(mrun, tmax);
          const float c = exp2f(mrun - mn);
          mrun = mn;
          lrun *= c;
#pragma unroll
          for (int r = 0; r < 4; ++r) {
            const float cq = __shfl(c, lg * 4 + r);
            o[0][r] *= cq; o[1][r] *= cq; o[2][r] *= cq; o[3][r] *= cq;
          }
        }
        // P = exp2(sc - mrun); pack 4 consecutive s as 2x cvt_pk -> ds_write_b64
        float psum = 0.f;
#pragma unroll
        for (int st = 0; st < 4; ++st) {
          const float p0 = exp2f(sc[st][0] - mrun);
          const float p1 = exp2f(sc[st][1] - mrun);
          const float p2 = exp2f(sc[st][2] - mrun);
          const float p3 = exp2f(sc[st][3] - mrun);
          psum += (p0 + p1) + (p2 + p3);
          const unsigned lo = cvt_pk_bf16(p0, p1);
          const unsigned hi = cvt_pk_bf16(p2, p3);
          const int off = l15 * 64 + SWZ(l15, st * 16 + lg * 4);
          *reinterpret_cast<uint2*>(Pw + off) = make_uint2(lo, hi);
        }
        psum += __shfl_xor(psum, 16);
        psum += __shfl_xor(psum, 32);
        lrun += psum;
        // PV: O[16q][64d] += P[16q][64s] * V[64s][64d]
        __builtin_amdgcn_s_setprio(1);
#pragma unroll
        for (int sc2 = 0; sc2 < 2; ++sc2) {
          const short8 pf =
              *reinterpret_cast<const short8*>(Pw + l15 * 64 + SWZ(l15, sc2 * 32 + lg * 8));
#pragma unroll
          for (int dt = 0; dt < 4; ++dt) {
            const int vr = dt * 16 + l15;
            const short8 vf =
                *reinterpret_cast<const short8*>(Vc + vr * 64 + SWZ(vr, sc2 * 32 + lg * 8));
            o[dt] = __builtin_amdgcn_mfma_f32_16x16x32_bf16(pf, vf, o[dt], 0, 0, 0);
          }
        }
        __builtin_amdgcn_s_setprio(0);
        __syncthreads();  // implicit vmcnt(0): next tile staged AND buf[cur] free
        cur ^= 1;
      }
    }
    // unnormalized partial write: partO[sx][bh*2048 + t][d], ml for lg==0
#pragma unroll
    for (int r = 0; r < 4; ++r) {
      const int t = qw + lg * 4 + r;
      const size_t base = ((size_t)sx * 65536 + (size_t)bh * 2048 + t) * 64;
#pragma unroll
      for (int dt = 0; dt < 4; ++dt) partO[base + dt * 16 + l15] = f2bf(o[dt][r]);
    }
    if (lg == 0) partML[sx * 65536 + bh * 2048 + qw + l15] = make_float2(mrun, lrun);
  }
}

// ---------------- combine the two s-halves -> ctx bf16 ----------------------
// 524288 threads; thread = (row R = bh*2048+t, 8-wide d chunk)
__global__ __launch_bounds__(256) void attn_combine(
    const unsigned short* __restrict__ partO, const float2* __restrict__ partML,
    unsigned short* __restrict__ ctx) {
  const int id = blockIdx.x * 256 + threadIdx.x;
  const int R = id >> 3;
  const int d8 = (id & 7) << 3;
  const float2 ml0 = partML[R];
  const float2 ml1 = partML[65536 + R];
  const float M = fmaxf(ml0.x, ml1.x);
  const float w0 = exp2f(ml0.x - M), w1 = exp2f(ml1.x - M);
  const float inv = __builtin_amdgcn_rcpf(ml0.y * w0 + ml1.y * w1);
  const short8 a = *reinterpret_cast<const short8*>(partO + ((size_t)R * 64 + d8));
  const short8 c = *reinterpret_cast<const short8*>(partO + ((size_t)(65536 + R) * 64 + d8));
  const int bh = R >> 11, t = R & 2047;
  const int b = bh >> 4, h = bh & 15;
  short8 outv;
#pragma unroll
  for (int e = 0; e < 8; ++e)
    outv[e] = (short)f2bf((bf2f((unsigned short)a[e]) * w0 +
                           bf2f((unsigned short)c[e]) * w1) * inv);
  *reinterpret_cast<short8*>(ctx + ((size_t)(b * 2048 + t) * 1024 + h * 64 + d8)) = outv;
}

// ---------------- launch ----------------------------------------------------
extern "C" void kernel_launch(void* const* d_in, const int* in_sizes, int n_in,
                              void* d_out, int out_size, void* d_ws, size_t ws_size,
                              hipStream_t stream) {
  const float* x = (const float*)d_in[0];
  const float* w_qkv = (const float*)d_in[1];
  const float* w_out = (const float*)d_in[2];
  // cache_k/cache_v/start_pos unused: start_pos=0, cache starts zero and is not returned.
  char* ws = (char*)d_ws;
  unsigned short* xb    = (unsigned short*)(ws);                       // 8 MiB
  unsigned short* wqkvb = (unsigned short*)(ws + (8ull  << 20));       // 6 MiB
  unsigned short* woutb = (unsigned short*)(ws + (14ull << 20));       // 2 MiB
  unsigned short* qkvb  = (unsigned short*)(ws + (16ull << 20));       // 24 MiB
  unsigned short* q_buf = (unsigned short*)(ws + (40ull << 20));       // 8 MiB
  unsigned short* k_buf = (unsigned short*)(ws + (48ull << 20));       // 8 MiB
  unsigned short* vt    = (unsigned short*)(ws + (56ull << 20));       // 8 MiB
  unsigned short* ctxb  = (unsigned short*)(ws + (64ull << 20));       // 8 MiB (total 72)
  // attn partials overlay the DEAD qkvb region (qkvb consumed by rope/v_transpose)
  unsigned short* partO = (unsigned short*)(ws + (16ull << 20));       // 16 MiB
  float2* partML        = (float2*)(ws + (32ull << 20));               // 1 MiB

  cast_f32_bf16<<<4096, 256, 0, stream>>>(x, xb, 4194304 / 4);
  cast_f32_bf16<<<3072, 256, 0, stream>>>(w_qkv, wqkvb, 3145728 / 4);
  cast_f32_bf16<<<1024, 256, 0, stream>>>(w_out, woutb, 1048576 / 4);
  gemm_nt<1><<<dim3(32, 24), 256, 0, stream>>>(xb, wqkvb, qkvb, 4096, 3072, 1024);
  rope_qk<<<16384, 256, 0, stream>>>(qkvb, q_buf, k_buf);
  v_transpose<<<dim3(32, 32), 256, 0, stream>>>(qkvb, vt);
  attn_kernel<<<dim3(32, 32), 256, 0, stream>>>(q_buf, k_buf, vt, partO, partML);
  attn_combine<<<2048, 256, 0, stream>>>(partO, partML, ctxb);
  gemm_nt<0><<<dim3(32, 8), 256, 0, stream>>>(ctxb, woutb, d_out, 4096, 1024, 1024);
}

// Round 7
// 135.809 us; speedup vs baseline: 1.6104x; 1.0470x over previous
//
#include <hip/hip_runtime.h>
#include <hip/hip_bf16.h>
#include <stdint.h>

typedef __attribute__((ext_vector_type(8))) short short8;
typedef __attribute__((ext_vector_type(4))) float f32x4;

static __device__ __forceinline__ unsigned short f2bf(float f) {
  union { float f; unsigned u; } v; v.f = f;
  return (unsigned short)((v.u + 0x7fffu + ((v.u >> 16) & 1u)) >> 16);
}
static __device__ __forceinline__ float bf2f(unsigned short h) {
  union { unsigned u; float f; } v; v.u = ((unsigned)h) << 16;
  return v.f;
}
// packed f32x2 -> bf16x2 (RNE), gfx950 (no builtin; T12 recipe)
static __device__ __forceinline__ unsigned cvt_pk_bf16(float lo, float hi) {
  unsigned r;
  asm("v_cvt_pk_bf16_f32 %0, %1, %2" : "=v"(r) : "v"(lo), "v"(hi));
  return r;
}

// async global->LDS, 16B per lane (guide §5; LDS dest = wave-uniform base + lane*16)
#define GLL16(gp, lp) __builtin_amdgcn_global_load_lds(                        \
    (__attribute__((address_space(1))) void*)(uintptr_t)(gp),                  \
    (__attribute__((address_space(3))) void*)(lp), 16, 0, 0)

// element-index XOR swizzle for 64-elem (128B) bf16 rows: spreads the
// 128B-stride column reads across 8 bank-granules (T2; involution).
#define SWZ(r, e) ((e) ^ (((r) & 7) << 3))

// ---------------- fused cast f32 -> bf16 for x, w_qkv, w_out ----------------
__global__ void cast3(const float* __restrict__ a, unsigned short* __restrict__ oa, int na4,
                      const float* __restrict__ b, unsigned short* __restrict__ ob, int nb4,
                      const float* __restrict__ c, unsigned short* __restrict__ oc, int nc4) {
  int i = blockIdx.x * 256 + threadIdx.x;
  const float* src;
  unsigned short* dst;
  int j = i;
  if (j < na4) { src = a; dst = oa; }
  else if ((j -= na4) < nb4) { src = b; dst = ob; }
  else { j -= nb4; if (j >= nc4) return; src = c; dst = oc; }
  const float4 v = reinterpret_cast<const float4*>(src)[j];
  ushort4 o;
  o.x = f2bf(v.x); o.y = f2bf(v.y); o.z = f2bf(v.z); o.w = f2bf(v.w);
  reinterpret_cast<ushort4*>(dst)[j] = o;
}

// ---------------- GEMM1 + fused RoPE/layout epilogue ------------------------
// C = x @ w_qkv^T [4096][3072]; epilogue writes directly:
//   cols [0,1024):    q -> RoPE, *1/sqrt(64)*log2e, q_buf[(b,h,t,d)] bf16
//   cols [1024,2048): k -> RoPE, k_buf[(b,h,t,d)] bf16
//   cols [2048,3072): v -> vt[(b,h,d,s)] bf16 (d-major for attn PV B-frags)
// RoPE pairs (d=2jj, 2jj+1) are adjacent lanes (col parity = l15&1):
// one __shfl_xor(1) supplies the partner; angles = h * 10000^(-jj/32).
__global__ __launch_bounds__(256) void gemm_qkv(
    const unsigned short* __restrict__ A, const unsigned short* __restrict__ B,
    unsigned short* __restrict__ qb, unsigned short* __restrict__ kb,
    unsigned short* __restrict__ vt) {
  constexpr int K = 1024;
  __shared__ unsigned short As[128 * 32];
  __shared__ unsigned short Bs[128 * 32];
  const int tid = threadIdx.x;
  const int lane = tid & 63;
  const int w = tid >> 6;
  const int wr = w >> 1, wc = w & 1;
  const int l15 = lane & 15, lg = lane >> 4;
  const size_t bm = (size_t)blockIdx.x * 128;
  const size_t bn = (size_t)blockIdx.y * 128;
  const unsigned short* Ab = A + bm * K;
  const unsigned short* Bb = B + bn * K;
  f32x4 acc[4][4];
#pragma unroll
  for (int m = 0; m < 4; ++m)
#pragma unroll
    for (int n = 0; n < 4; ++n) acc[m][n] = (f32x4){0.f, 0.f, 0.f, 0.f};

  for (int k0 = 0; k0 < K; k0 += 32) {
    __syncthreads();
#pragma unroll
    for (int p = 0; p < 2; ++p) {
      const int flat = p * 256 + tid;
      const int row = flat >> 2;
      const int c8 = (flat & 3) << 3;
      GLL16(Ab + (size_t)row * K + k0 + c8, As + flat * 8);
      GLL16(Bb + (size_t)row * K + k0 + c8, Bs + flat * 8);
    }
    __syncthreads();
    short8 af[4], bf[4];
#pragma unroll
    for (int m = 0; m < 4; ++m)
      af[m] = *reinterpret_cast<const short8*>(As + ((wr * 64 + m * 16 + l15) * 32 + lg * 8));
#pragma unroll
    for (int n = 0; n < 4; ++n)
      bf[n] = *reinterpret_cast<const short8*>(Bs + ((wc * 64 + n * 16 + l15) * 32 + lg * 8));
#pragma unroll
    for (int m = 0; m < 4; ++m)
#pragma unroll
      for (int n = 0; n < 4; ++n)
        acc[m][n] = __builtin_amdgcn_mfma_f32_16x16x32_bf16(af[m], bf[n], acc[m][n], 0, 0, 0);
  }
  const int sec = (int)(bn >> 10);                 // 0=q 1=k 2=v (block-uniform)
  const int row0 = (int)bm + wr * 64 + lg * 4;     // + m*16 + r -> b*2048+t
  const int c0 = (int)(bn & 1023) + wc * 64 + l15; // col within section, + n*16
  if (sec < 2) {
    unsigned short* dst = sec ? kb : qb;
    const float scl = sec ? 1.0f : (0.125f * 1.44269504089f);  // q: 1/sqrt(D)*log2e
    const int par = l15 & 1;
#pragma unroll
    for (int n = 0; n < 4; ++n) {
      const int cq = c0 + n * 16;
      const int h = cq >> 6, d = cq & 63, jj = (cq & 63) >> 1;
      const float freq = __expf(-(float)jj * (9.210340371976184f / 32.0f));  // ln(1e4)/32
      float sn, cs;
      __sincosf((float)h * freq, &sn, &cs);
#pragma unroll
      for (int m = 0; m < 4; ++m)
#pragma unroll
        for (int r = 0; r < 4; ++r) {
          const float v = acc[m][n][r];
          const float p = __shfl_xor(v, 1);  // partner element of the RoPE pair
          const float o = par ? (p * sn + v * cs) : (v * cs - p * sn);
          const int row = row0 + m * 16 + r;
          const int b = row >> 11, t = row & 2047;
          dst[(((size_t)(b * 16 + h) * 2048 + t) << 6) + d] = f2bf(o * scl);
        }
    }
  } else {
#pragma unroll
    for (int n = 0; n < 4; ++n) {
      const int cv = c0 + n * 16;
      const int h = cv >> 6, d = cv & 63;
#pragma unroll
      for (int m = 0; m < 4; ++m) {
        const int row = row0 + m * 16;  // r=0..3 are consecutive t (8B store)
        const int b = row >> 11, t = row & 2047;
        ushort4 pk;
        pk.x = f2bf(acc[m][n][0]); pk.y = f2bf(acc[m][n][1]);
        pk.z = f2bf(acc[m][n][2]); pk.w = f2bf(acc[m][n][3]);
        *reinterpret_cast<ushort4*>(
            vt + ((size_t)((b * 16 + h) * 64 + d) * 2048 + t)) = pk;
      }
    }
  }
}

// ---------------- NT GEMM (output fp32): C = ctx @ w_out^T ------------------
__global__ __launch_bounds__(256) void gemm_nt_f32(
    const unsigned short* __restrict__ A, const unsigned short* __restrict__ B,
    float* __restrict__ Cout, int M, int N, int K) {
  __shared__ unsigned short As[128 * 32];
  __shared__ unsigned short Bs[128 * 32];
  const int tid = threadIdx.x;
  const int lane = tid & 63;
  const int w = tid >> 6;
  const int wr = w >> 1, wc = w & 1;
  const int l15 = lane & 15, lg = lane >> 4;
  const size_t bm = (size_t)blockIdx.x * 128;
  const size_t bn = (size_t)blockIdx.y * 128;
  const unsigned short* Ab = A + bm * K;
  const unsigned short* Bb = B + bn * K;
  f32x4 acc[4][4];
#pragma unroll
  for (int m = 0; m < 4; ++m)
#pragma unroll
    for (int n = 0; n < 4; ++n) acc[m][n] = (f32x4){0.f, 0.f, 0.f, 0.f};

  for (int k0 = 0; k0 < K; k0 += 32) {
    __syncthreads();
#pragma unroll
    for (int p = 0; p < 2; ++p) {
      const int flat = p * 256 + tid;
      const int row = flat >> 2;
      const int c8 = (flat & 3) << 3;
      GLL16(Ab + (size_t)row * K + k0 + c8, As + flat * 8);
      GLL16(Bb + (size_t)row * K + k0 + c8, Bs + flat * 8);
    }
    __syncthreads();
    short8 af[4], bf[4];
#pragma unroll
    for (int m = 0; m < 4; ++m)
      af[m] = *reinterpret_cast<const short8*>(As + ((wr * 64 + m * 16 + l15) * 32 + lg * 8));
#pragma unroll
    for (int n = 0; n < 4; ++n)
      bf[n] = *reinterpret_cast<const short8*>(Bs + ((wc * 64 + n * 16 + l15) * 32 + lg * 8));
#pragma unroll
    for (int m = 0; m < 4; ++m)
#pragma unroll
      for (int n = 0; n < 4; ++n)
        acc[m][n] = __builtin_amdgcn_mfma_f32_16x16x32_bf16(af[m], bf[n], acc[m][n], 0, 0, 0);
  }
  const size_t row0 = bm + wr * 64 + lg * 4;
  const size_t col0 = bn + wc * 64 + l15;
#pragma unroll
  for (int m = 0; m < 4; ++m)
#pragma unroll
    for (int n = 0; n < 4; ++n)
#pragma unroll
      for (int r = 0; r < 4; ++r)
        Cout[(row0 + m * 16 + r) * N + col0 + n * 16] = acc[m][n][r];
}

// ---------------- flash attention, causal, s-split x2 + partials ------------
// grid (32, B*H): px = x>>1 pairs q-tiles (px, 31-px); sx = x&1 selects the
// lower/upper half of each q-tile's s-range -> uniform ~16.5 tile-units/block.
// Emits unnormalized partials (O bf16, m/l f32); attn_combine merges.
__global__ __launch_bounds__(256) void attn_kernel(
    const unsigned short* __restrict__ qb, const unsigned short* __restrict__ kb,
    const unsigned short* __restrict__ vt, unsigned short* __restrict__ partO,
    float2* __restrict__ partML) {
  __shared__ unsigned short Ks[2][64 * 64];  // [s][d], swizzled
  __shared__ unsigned short Vs[2][64 * 64];  // [d][s], swizzled
  __shared__ unsigned short Ps[4][16 * 64];  // per-wave P [q][s], swizzled
  const int tid = threadIdx.x;
  const int lane = tid & 63;
  const int w = tid >> 6;
  const int l15 = lane & 15, lg = lane >> 4;
  const int sx = blockIdx.x & 1, px = blockIdx.x >> 1;
  const int bh = blockIdx.y;
  unsigned short* Pw = &Ps[w][0];

  const unsigned short* kg[2];
  const unsigned short* vg[2];
#pragma unroll
  for (int p = 0; p < 2; ++p) {
    const int f = p * 256 + tid;
    const int row = f >> 3;
    const int gc8 = SWZ(row, (f & 7) << 3);
    kg[p] = kb + ((size_t)bh * 2048 + row) * 64 + gc8;
    vg[p] = vt + ((size_t)bh * 64 + row) * 2048 + gc8;
  }

  int cur = 0;
#pragma unroll 1
  for (int mem = 0; mem < 2; ++mem) {
    const int qt = mem ? (31 - px) : px;
    const int nt = qt + 1;
    const int mid = (nt + 1) >> 1;
    const int sb = sx ? mid : 0;
    const int se = sx ? nt : mid;
    const int nh = se - sb;
    const int qw = qt * 64 + w * 16;
    const unsigned short* Qp = qb + ((size_t)bh * 2048 + qw) * 64;
    const short8 qf0 = *reinterpret_cast<const short8*>(Qp + (size_t)l15 * 64 + lg * 8);
    const short8 qf1 = *reinterpret_cast<const short8*>(Qp + (size_t)l15 * 64 + 32 + lg * 8);
    float mrun = -1e30f, lrun = 0.f;
    f32x4 o[4];
#pragma unroll
    for (int dt = 0; dt < 4; ++dt) o[dt] = (f32x4){0.f, 0.f, 0.f, 0.f};

    if (nh > 0) {
#pragma unroll
      for (int p = 0; p < 2; ++p) {
        const int f = p * 256 + tid;
        GLL16(kg[p] + (size_t)sb * 64 * 64, &Ks[cur][f * 8]);
        GLL16(vg[p] + (size_t)sb * 64, &Vs[cur][f * 8]);
      }
      __syncthreads();

#pragma unroll 1
      for (int it = 0; it < nh; ++it) {
        const int ti = sb + it;
        const int s0 = ti * 64;
        if (it + 1 < nh) {
#pragma unroll
          for (int p = 0; p < 2; ++p) {
            const int f = p * 256 + tid;
            GLL16(kg[p] + (size_t)(ti + 1) * 64 * 64, &Ks[cur ^ 1][f * 8]);
            GLL16(vg[p] + (size_t)(ti + 1) * 64, &Vs[cur ^ 1][f * 8]);
          }
        }
        const unsigned short* Kc = &Ks[cur][0];
        const unsigned short* Vc = &Vs[cur][0];
        f32x4 sc[4];
        __builtin_amdgcn_s_setprio(1);
#pragma unroll
        for (int st = 0; st < 4; ++st) {
          const int kr = st * 16 + l15;
          const short8 kf0 = *reinterpret_cast<const short8*>(Kc + kr * 64 + SWZ(kr, lg * 8));
          const short8 kf1 = *reinterpret_cast<const short8*>(Kc + kr * 64 + SWZ(kr, 32 + lg * 8));
          f32x4 z = (f32x4){0.f, 0.f, 0.f, 0.f};
          z = __builtin_amdgcn_mfma_f32_16x16x32_bf16(kf0, qf0, z, 0, 0, 0);
          z = __builtin_amdgcn_mfma_f32_16x16x32_bf16(kf1, qf1, z, 0, 0, 0);
          sc[st] = z;
        }
        __builtin_amdgcn_s_setprio(0);
        if (s0 + 63 > qw) {
          const int sbase = s0 + lg * 4 - qw - l15;
#pragma unroll
          for (int st = 0; st < 4; ++st)
#pragma unroll
            for (int r = 0; r < 4; ++r)
              if (sbase + st * 16 + r > 0) sc[st][r] = -1e30f;
        }
        float tmax = sc[0][0];
#pragma unroll
        for (int st = 0; st < 4; ++st)
#pragma unroll
          for (int r = 0; r < 4; ++r) tmax = fmaxf(tmax, sc[st][r]);
        tmax = fmaxf(tmax, __shfl_xor(tmax, 16));
        tmax = fmaxf(tmax, __shfl_xor(tmax, 32));
        if (__any(tmax > mrun + 8.f)) {
          const float mn = fmaxf(mrun, tmax);
          const float c = exp2f(mrun - mn);
          mrun = mn;
          lrun *= c;
#pragma unroll
          for (int r = 0; r < 4; ++r) {
            const float cq = __shfl(c, lg * 4 + r);
            o[0][r] *= cq; o[1][r] *= cq; o[2][r] *= cq; o[3][r] *= cq;
          }
        }
        float psum = 0.f;
#pragma unroll
        for (int st = 0; st < 4; ++st) {
          const float p0 = exp2f(sc[st][0] - mrun);
          const float p1 = exp2f(sc[st][1] - mrun);
          const float p2 = exp2f(sc[st][2] - mrun);
          const float p3 = exp2f(sc[st][3] - mrun);
          psum += (p0 + p1) + (p2 + p3);
          const unsigned lo = cvt_pk_bf16(p0, p1);
          const unsigned hi = cvt_pk_bf16(p2, p3);
          const int off = l15 * 64 + SWZ(l15, st * 16 + lg * 4);
          *reinterpret_cast<uint2*>(Pw + off) = make_uint2(lo, hi);
        }
        psum += __shfl_xor(psum, 16);
        psum += __shfl_xor(psum, 32);
        lrun += psum;
        __builtin_amdgcn_s_setprio(1);
#pragma unroll
        for (int sc2 = 0; sc2 < 2; ++sc2) {
          const short8 pf =
              *reinterpret_cast<const short8*>(Pw + l15 * 64 + SWZ(l15, sc2 * 32 + lg * 8));
#pragma unroll
          for (int dt = 0; dt < 4; ++dt) {
            const int vr = dt * 16 + l15;
            const short8 vf =
                *reinterpret_cast<const short8*>(Vc + vr * 64 + SWZ(vr, sc2 * 32 + lg * 8));
            o[dt] = __builtin_amdgcn_mfma_f32_16x16x32_bf16(pf, vf, o[dt], 0, 0, 0);
          }
        }
        __builtin_amdgcn_s_setprio(0);
        __syncthreads();
        cur ^= 1;
      }
    }
#pragma unroll
    for (int r = 0; r < 4; ++r) {
      const int t = qw + lg * 4 + r;
      const size_t base = ((size_t)sx * 65536 + (size_t)bh * 2048 + t) * 64;
#pragma unroll
      for (int dt = 0; dt < 4; ++dt) partO[base + dt * 16 + l15] = f2bf(o[dt][r]);
    }
    if (lg == 0) partML[sx * 65536 + bh * 2048 + qw + l15] = make_float2(mrun, lrun);
  }
}

// ---------------- combine the two s-halves -> ctx bf16 ----------------------
__global__ __launch_bounds__(256) void attn_combine(
    const unsigned short* __restrict__ partO, const float2* __restrict__ partML,
    unsigned short* __restrict__ ctx) {
  const int id = blockIdx.x * 256 + threadIdx.x;
  const int R = id >> 3;
  const int d8 = (id & 7) << 3;
  const float2 ml0 = partML[R];
  const float2 ml1 = partML[65536 + R];
  const float M = fmaxf(ml0.x, ml1.x);
  const float w0 = exp2f(ml0.x - M), w1 = exp2f(ml1.x - M);
  const float inv = __builtin_amdgcn_rcpf(ml0.y * w0 + ml1.y * w1);
  const short8 a = *reinterpret_cast<const short8*>(partO + ((size_t)R * 64 + d8));
  const short8 c = *reinterpret_cast<const short8*>(partO + ((size_t)(65536 + R) * 64 + d8));
  const int bh = R >> 11, t = R & 2047;
  const int b = bh >> 4, h = bh & 15;
  short8 outv;
#pragma unroll
  for (int e = 0; e < 8; ++e)
    outv[e] = (short)f2bf((bf2f((unsigned short)a[e]) * w0 +
                           bf2f((unsigned short)c[e]) * w1) * inv);
  *reinterpret_cast<short8*>(ctx + ((size_t)(b * 2048 + t) * 1024 + h * 64 + d8)) = outv;
}

// ---------------- launch ----------------------------------------------------
extern "C" void kernel_launch(void* const* d_in, const int* in_sizes, int n_in,
                              void* d_out, int out_size, void* d_ws, size_t ws_size,
                              hipStream_t stream) {
  const float* x = (const float*)d_in[0];
  const float* w_qkv = (const float*)d_in[1];
  const float* w_out = (const float*)d_in[2];
  // cache_k/cache_v/start_pos unused: start_pos=0, cache starts zero and is not returned.
  char* ws = (char*)d_ws;
  unsigned short* xb    = (unsigned short*)(ws);                       // 8 MiB
  unsigned short* wqkvb = (unsigned short*)(ws + (8ull  << 20));       // 6 MiB
  unsigned short* woutb = (unsigned short*)(ws + (14ull << 20));       // 2 MiB
  unsigned short* partO = (unsigned short*)(ws + (16ull << 20));       // 16 MiB
  float2* partML        = (float2*)(ws + (32ull << 20));               // 1 MiB
  unsigned short* q_buf = (unsigned short*)(ws + (40ull << 20));       // 8 MiB
  unsigned short* k_buf = (unsigned short*)(ws + (48ull << 20));       // 8 MiB
  unsigned short* vt    = (unsigned short*)(ws + (56ull << 20));       // 8 MiB
  unsigned short* ctxb  = (unsigned short*)(ws + (64ull << 20));       // 8 MiB (total 72)

  cast3<<<8192, 256, 0, stream>>>(x, xb, 1048576, w_qkv, wqkvb, 786432,
                                  w_out, woutb, 262144);
  gemm_qkv<<<dim3(32, 24), 256, 0, stream>>>(xb, wqkvb, q_buf, k_buf, vt);
  attn_kernel<<<dim3(32, 32), 256, 0, stream>>>(q_buf, k_buf, vt, partO, partML);
  attn_combine<<<2048, 256, 0, stream>>>(partO, partML, ctxb);
  gemm_nt_f32<<<dim3(32, 8), 256, 0, stream>>>(ctxb, woutb, (float*)d_out, 4096, 1024, 1024);
}

// Round 8
// 135.490 us; speedup vs baseline: 1.6141x; 1.0023x over previous
//
#include <hip/hip_runtime.h>
#include <hip/hip_bf16.h>
#include <stdint.h>

typedef __attribute__((ext_vector_type(8))) short short8;
typedef __attribute__((ext_vector_type(4))) float f32x4;

static __device__ __forceinline__ unsigned short f2bf(float f) {
  union { float f; unsigned u; } v; v.f = f;
  return (unsigned short)((v.u + 0x7fffu + ((v.u >> 16) & 1u)) >> 16);
}
static __device__ __forceinline__ float bf2f(unsigned short h) {
  union { unsigned u; float f; } v; v.u = ((unsigned)h) << 16;
  return v.f;
}
// packed f32x2 -> bf16x2 (RNE), gfx950 (no builtin; T12 recipe)
static __device__ __forceinline__ unsigned cvt_pk_bf16(float lo, float hi) {
  unsigned r;
  asm("v_cvt_pk_bf16_f32 %0, %1, %2" : "=v"(r) : "v"(lo), "v"(hi));
  return r;
}

// async global->LDS, 16B per lane (guide §5; LDS dest = wave-uniform base + lane*16)
#define GLL16(gp, lp) __builtin_amdgcn_global_load_lds(                        \
    (__attribute__((address_space(1))) void*)(uintptr_t)(gp),                  \
    (__attribute__((address_space(3))) void*)(lp), 16, 0, 0)

// element-index XOR swizzle for 64-elem (128B) bf16 rows: spreads the
// 128B-stride column reads across 8 bank-granules (T2; involution).
#define SWZ(r, e) ((e) ^ (((r) & 7) << 3))

// ---------------- fused cast f32 -> bf16 for x, w_qkv, w_out ----------------
__global__ void cast3(const float* __restrict__ a, unsigned short* __restrict__ oa, int na4,
                      const float* __restrict__ b, unsigned short* __restrict__ ob, int nb4,
                      const float* __restrict__ c, unsigned short* __restrict__ oc, int nc4) {
  int i = blockIdx.x * 256 + threadIdx.x;
  const float* src;
  unsigned short* dst;
  int j = i;
  if (j < na4) { src = a; dst = oa; }
  else if ((j -= na4) < nb4) { src = b; dst = ob; }
  else { j -= nb4; if (j >= nc4) return; src = c; dst = oc; }
  const float4 v = reinterpret_cast<const float4*>(src)[j];
  ushort4 o;
  o.x = f2bf(v.x); o.y = f2bf(v.y); o.z = f2bf(v.z); o.w = f2bf(v.w);
  reinterpret_cast<ushort4*>(dst)[j] = o;
}

// ---------------- GEMM1 + fused RoPE/layout epilogue (LDS-staged) -----------
// C = x @ w_qkv^T [4096][3072]; epilogue stages the C-tile in LDS (pitch 136)
// and emits coalesced stores:
//   cols [0,1024):    q -> RoPE, *1/sqrt(64)*log2e, q_buf[(b,h,t,d)] bf16
//   cols [1024,2048): k -> RoPE, k_buf[(b,h,t,d)] bf16
//   cols [2048,3072): v -> vt[(b,h,d,s)] bf16 (d-major; [c][t] staging, granule swizzle)
// RoPE pairs (d=2jj,2jj+1) are adjacent lanes; even lane computes both rotated
// values and writes one packed dword to LDS (halves LDS writes).
__global__ __launch_bounds__(256) void gemm_qkv(
    const unsigned short* __restrict__ A, const unsigned short* __restrict__ B,
    unsigned short* __restrict__ qb, unsigned short* __restrict__ kb,
    unsigned short* __restrict__ vt) {
  constexpr int K = 1024;
  __shared__ unsigned short smem[128 * 136];  // K-loop: As/Bs (16KB); epilogue: 34KB stage
  unsigned short* As = smem;
  unsigned short* Bs = smem + 128 * 32;
  const int tid = threadIdx.x;
  const int lane = tid & 63;
  const int w = tid >> 6;
  const int wr = w >> 1, wc = w & 1;
  const int l15 = lane & 15, lg = lane >> 4;
  const size_t bm = (size_t)blockIdx.x * 128;
  const size_t bn = (size_t)blockIdx.y * 128;
  const unsigned short* Ab = A + bm * K;
  const unsigned short* Bb = B + bn * K;
  f32x4 acc[4][4];
#pragma unroll
  for (int m = 0; m < 4; ++m)
#pragma unroll
    for (int n = 0; n < 4; ++n) acc[m][n] = (f32x4){0.f, 0.f, 0.f, 0.f};

  for (int k0 = 0; k0 < K; k0 += 32) {
    __syncthreads();
#pragma unroll
    for (int p = 0; p < 2; ++p) {
      const int flat = p * 256 + tid;
      const int row = flat >> 2;
      const int c8 = (flat & 3) << 3;
      GLL16(Ab + (size_t)row * K + k0 + c8, As + flat * 8);
      GLL16(Bb + (size_t)row * K + k0 + c8, Bs + flat * 8);
    }
    __syncthreads();
    short8 af[4], bf[4];
#pragma unroll
    for (int m = 0; m < 4; ++m)
      af[m] = *reinterpret_cast<const short8*>(As + ((wr * 64 + m * 16 + l15) * 32 + lg * 8));
#pragma unroll
    for (int n = 0; n < 4; ++n)
      bf[n] = *reinterpret_cast<const short8*>(Bs + ((wc * 64 + n * 16 + l15) * 32 + lg * 8));
#pragma unroll
    for (int m = 0; m < 4; ++m)
#pragma unroll
      for (int n = 0; n < 4; ++n)
        acc[m][n] = __builtin_amdgcn_mfma_f32_16x16x32_bf16(af[m], bf[n], acc[m][n], 0, 0, 0);
  }

  __syncthreads();  // all frag reads done; smem is now the staging tile
  const int sec = (int)(bn >> 10);                 // 0=q 1=k 2=v (block-uniform)
  const int hbase = (int)((bn & 1023) >> 6);
  if (sec < 2) {
    // ---- q/k: RoPE in regs, stage [t][c] as packed dwords ----
    unsigned* st32 = reinterpret_cast<unsigned*>(smem);
    const float scl = sec ? 1.0f : (0.125f * 1.44269504089f);  // q: 1/sqrt(D)*log2e
    const bool even = (l15 & 1) == 0;
#pragma unroll
    for (int n = 0; n < 4; ++n) {
      const int c = wc * 64 + n * 16 + l15;        // local col 0..127
      const int jj = (c & 63) >> 1;
      const int h = hbase + (c >> 6);
      const float freq = __expf(-(float)jj * (9.210340371976184f / 32.0f));  // ln(1e4)/32
      float sn, cs;
      __sincosf((float)h * freq, &sn, &cs);
#pragma unroll
      for (int m = 0; m < 4; ++m)
#pragma unroll
        for (int r = 0; r < 4; ++r) {
          const float v = acc[m][n][r];
          const float p = __shfl_xor(v, 1);        // partner of the RoPE pair
          if (even) {                              // even lane emits both outputs
            const float o0 = (v * cs - p * sn) * scl;
            const float o1 = (v * sn + p * cs) * scl;
            const int tl = wr * 64 + lg * 4 + m * 16 + r;
            st32[tl * 68 + (c >> 1)] = cvt_pk_bf16(o0, o1);
          }
        }
    }
    __syncthreads();
    unsigned short* dst = sec ? kb : qb;
#pragma unroll
    for (int p8 = 0; p8 < 8; ++p8) {
      const int id = p8 * 256 + tid;               // 2048 ushort8-chunks
      const int tlc = id >> 4, cch = id & 15;
      const short8 val = *reinterpret_cast<const short8*>(smem + tlc * 136 + cch * 8);
      const int trow = (int)bm + tlc;
      const int b = trow >> 11, t = trow & 2047;
      const int h = hbase + (cch >> 3), d0 = (cch & 7) * 8;
      *reinterpret_cast<short8*>(dst + (((size_t)(b * 16 + h) * 2048 + t) << 6) + d0) = val;
    }
  } else {
    // ---- v: stage [c][t] with 4-elem-granule swizzle, coalesced d-major out ----
#pragma unroll
    for (int n = 0; n < 4; ++n) {
      const int c = wc * 64 + n * 16 + l15;
      const int x = (c & 7) << 2;
#pragma unroll
      for (int m = 0; m < 4; ++m) {
        const int gt = wr * 16 + lg + m * 4;       // t-granule index (4 t each)
        ushort4 pk;
        pk.x = f2bf(acc[m][n][0]); pk.y = f2bf(acc[m][n][1]);
        pk.z = f2bf(acc[m][n][2]); pk.w = f2bf(acc[m][n][3]);
        *reinterpret_cast<ushort4*>(smem + c * 136 + ((gt ^ x) << 2)) = pk;
      }
    }
    __syncthreads();
#pragma unroll
    for (int p8 = 0; p8 < 8; ++p8) {
      const int id = p8 * 256 + tid;
      const int cl = id >> 4, tch = id & 15;
      const int x = (cl & 7) << 2;
      const short8 val =
          *reinterpret_cast<const short8*>(smem + cl * 136 + (((tch * 2) ^ x) << 2));
      const int col = (int)(bn & 1023) + cl;
      const int h = col >> 6, d = col & 63;
      const int trow = (int)bm + tch * 8;
      const int b = trow >> 11, t = trow & 2047;
      *reinterpret_cast<short8*>(vt + ((size_t)((b * 16 + h) * 64 + d)) * 2048 + t) = val;
    }
  }
}

// ---------------- NT GEMM (output fp32): C = ctx @ w_out^T ------------------
__global__ __launch_bounds__(256) void gemm_nt_f32(
    const unsigned short* __restrict__ A, const unsigned short* __restrict__ B,
    float* __restrict__ Cout, int M, int N, int K) {
  __shared__ unsigned short As[128 * 32];
  __shared__ unsigned short Bs[128 * 32];
  const int tid = threadIdx.x;
  const int lane = tid & 63;
  const int w = tid >> 6;
  const int wr = w >> 1, wc = w & 1;
  const int l15 = lane & 15, lg = lane >> 4;
  const size_t bm = (size_t)blockIdx.x * 128;
  const size_t bn = (size_t)blockIdx.y * 128;
  const unsigned short* Ab = A + bm * K;
  const unsigned short* Bb = B + bn * K;
  f32x4 acc[4][4];
#pragma unroll
  for (int m = 0; m < 4; ++m)
#pragma unroll
    for (int n = 0; n < 4; ++n) acc[m][n] = (f32x4){0.f, 0.f, 0.f, 0.f};

  for (int k0 = 0; k0 < K; k0 += 32) {
    __syncthreads();
#pragma unroll
    for (int p = 0; p < 2; ++p) {
      const int flat = p * 256 + tid;
      const int row = flat >> 2;
      const int c8 = (flat & 3) << 3;
      GLL16(Ab + (size_t)row * K + k0 + c8, As + flat * 8);
      GLL16(Bb + (size_t)row * K + k0 + c8, Bs + flat * 8);
    }
    __syncthreads();
    short8 af[4], bf[4];
#pragma unroll
    for (int m = 0; m < 4; ++m)
      af[m] = *reinterpret_cast<const short8*>(As + ((wr * 64 + m * 16 + l15) * 32 + lg * 8));
#pragma unroll
    for (int n = 0; n < 4; ++n)
      bf[n] = *reinterpret_cast<const short8*>(Bs + ((wc * 64 + n * 16 + l15) * 32 + lg * 8));
#pragma unroll
    for (int m = 0; m < 4; ++m)
#pragma unroll
      for (int n = 0; n < 4; ++n)
        acc[m][n] = __builtin_amdgcn_mfma_f32_16x16x32_bf16(af[m], bf[n], acc[m][n], 0, 0, 0);
  }
  const size_t row0 = bm + wr * 64 + lg * 4;
  const size_t col0 = bn + wc * 64 + l15;
#pragma unroll
  for (int m = 0; m < 4; ++m)
#pragma unroll
    for (int n = 0; n < 4; ++n)
#pragma unroll
      for (int r = 0; r < 4; ++r)
        Cout[(row0 + m * 16 + r) * N + col0 + n * 16] = acc[m][n][r];
}

// ---------------- flash attention, causal, s-split x2 + partials ------------
// grid (32, B*H): px = x>>1 pairs q-tiles (px, 31-px); sx = x&1 selects the
// lower/upper half of each q-tile's s-range -> uniform ~16.5 tile-units/block.
// Emits unnormalized partials (O bf16, m/l f32); attn_combine merges.
__global__ __launch_bounds__(256) void attn_kernel(
    const unsigned short* __restrict__ qb, const unsigned short* __restrict__ kb,
    const unsigned short* __restrict__ vt, unsigned short* __restrict__ partO,
    float2* __restrict__ partML) {
  __shared__ unsigned short Ks[2][64 * 64];  // [s][d], swizzled
  __shared__ unsigned short Vs[2][64 * 64];  // [d][s], swizzled
  __shared__ unsigned short Ps[4][16 * 64];  // per-wave P [q][s], swizzled
  const int tid = threadIdx.x;
  const int lane = tid & 63;
  const int w = tid >> 6;
  const int l15 = lane & 15, lg = lane >> 4;
  const int sx = blockIdx.x & 1, px = blockIdx.x >> 1;
  const int bh = blockIdx.y;
  unsigned short* Pw = &Ps[w][0];

  const unsigned short* kg[2];
  const unsigned short* vg[2];
#pragma unroll
  for (int p = 0; p < 2; ++p) {
    const int f = p * 256 + tid;
    const int row = f >> 3;
    const int gc8 = SWZ(row, (f & 7) << 3);
    kg[p] = kb + ((size_t)bh * 2048 + row) * 64 + gc8;
    vg[p] = vt + ((size_t)bh * 64 + row) * 2048 + gc8;
  }

  int cur = 0;
#pragma unroll 1
  for (int mem = 0; mem < 2; ++mem) {
    const int qt = mem ? (31 - px) : px;
    const int nt = qt + 1;
    const int mid = (nt + 1) >> 1;
    const int sb = sx ? mid : 0;
    const int se = sx ? nt : mid;
    const int nh = se - sb;
    const int qw = qt * 64 + w * 16;
    const unsigned short* Qp = qb + ((size_t)bh * 2048 + qw) * 64;
    const short8 qf0 = *reinterpret_cast<const short8*>(Qp + (size_t)l15 * 64 + lg * 8);
    const short8 qf1 = *reinterpret_cast<const short8*>(Qp + (size_t)l15 * 64 + 32 + lg * 8);
    float mrun = -1e30f, lrun = 0.f;
    f32x4 o[4];
#pragma unroll
    for (int dt = 0; dt < 4; ++dt) o[dt] = (f32x4){0.f, 0.f, 0.f, 0.f};

    if (nh > 0) {
#pragma unroll
      for (int p = 0; p < 2; ++p) {
        const int f = p * 256 + tid;
        GLL16(kg[p] + (size_t)sb * 64 * 64, &Ks[cur][f * 8]);
        GLL16(vg[p] + (size_t)sb * 64, &Vs[cur][f * 8]);
      }
      __syncthreads();

#pragma unroll 1
      for (int it = 0; it < nh; ++it) {
        const int ti = sb + it;
        const int s0 = ti * 64;
        if (it + 1 < nh) {
#pragma unroll
          for (int p = 0; p < 2; ++p) {
            const int f = p * 256 + tid;
            GLL16(kg[p] + (size_t)(ti + 1) * 64 * 64, &Ks[cur ^ 1][f * 8]);
            GLL16(vg[p] + (size_t)(ti + 1) * 64, &Vs[cur ^ 1][f * 8]);
          }
        }
        const unsigned short* Kc = &Ks[cur][0];
        const unsigned short* Vc = &Vs[cur][0];
        f32x4 sc[4];
        __builtin_amdgcn_s_setprio(1);
#pragma unroll
        for (int st = 0; st < 4; ++st) {
          const int kr = st * 16 + l15;
          const short8 kf0 = *reinterpret_cast<const short8*>(Kc + kr * 64 + SWZ(kr, lg * 8));
          const short8 kf1 = *reinterpret_cast<const short8*>(Kc + kr * 64 + SWZ(kr, 32 + lg * 8));
          f32x4 z = (f32x4){0.f, 0.f, 0.f, 0.f};
          z = __builtin_amdgcn_mfma_f32_16x16x32_bf16(kf0, qf0, z, 0, 0, 0);
          z = __builtin_amdgcn_mfma_f32_16x16x32_bf16(kf1, qf1, z, 0, 0, 0);
          sc[st] = z;
        }
        __builtin_amdgcn_s_setprio(0);
        if (s0 + 63 > qw) {
          const int sbase = s0 + lg * 4 - qw - l15;
#pragma unroll
          for (int st = 0; st < 4; ++st)
#pragma unroll
            for (int r = 0; r < 4; ++r)
              if (sbase + st * 16 + r > 0) sc[st][r] = -1e30f;
        }
        float tmax = sc[0][0];
#pragma unroll
        for (int st = 0; st < 4; ++st)
#pragma unroll
          for (int r = 0; r < 4; ++r) tmax = fmaxf(tmax, sc[st][r]);
        tmax = fmaxf(tmax, __shfl_xor(tmax, 16));
        tmax = fmaxf(tmax, __shfl_xor(tmax, 32));
        if (__any(tmax > mrun + 8.f)) {
          const float mn = fmaxf(mrun, tmax);
          const float c = exp2f(mrun - mn);
          mrun = mn;
          lrun *= c;
#pragma unroll
          for (int r = 0; r < 4; ++r) {
            const float cq = __shfl(c, lg * 4 + r);
            o[0][r] *= cq; o[1][r] *= cq; o[2][r] *= cq; o[3][r] *= cq;
          }
        }
        float psum = 0.f;
#pragma unroll
        for (int st = 0; st < 4; ++st) {
          const float p0 = exp2f(sc[st][0] - mrun);
          const float p1 = exp2f(sc[st][1] - mrun);
          const float p2 = exp2f(sc[st][2] - mrun);
          const float p3 = exp2f(sc[st][3] - mrun);
          psum += (p0 + p1) + (p2 + p3);
          const unsigned lo = cvt_pk_bf16(p0, p1);
          const unsigned hi = cvt_pk_bf16(p2, p3);
          const int off = l15 * 64 + SWZ(l15, st * 16 + lg * 4);
          *reinterpret_cast<uint2*>(Pw + off) = make_uint2(lo, hi);
        }
        psum += __shfl_xor(psum, 16);
        psum += __shfl_xor(psum, 32);
        lrun += psum;
        __builtin_amdgcn_s_setprio(1);
#pragma unroll
        for (int sc2 = 0; sc2 < 2; ++sc2) {
          const short8 pf =
              *reinterpret_cast<const short8*>(Pw + l15 * 64 + SWZ(l15, sc2 * 32 + lg * 8));
#pragma unroll
          for (int dt = 0; dt < 4; ++dt) {
            const int vr = dt * 16 + l15;
            const short8 vf =
                *reinterpret_cast<const short8*>(Vc + vr * 64 + SWZ(vr, sc2 * 32 + lg * 8));
            o[dt] = __builtin_amdgcn_mfma_f32_16x16x32_bf16(pf, vf, o[dt], 0, 0, 0);
          }
        }
        __builtin_amdgcn_s_setprio(0);
        __syncthreads();
        cur ^= 1;
      }
    }
#pragma unroll
    for (int r = 0; r < 4; ++r) {
      const int t = qw + lg * 4 + r;
      const size_t base = ((size_t)sx * 65536 + (size_t)bh * 2048 + t) * 64;
#pragma unroll
      for (int dt = 0; dt < 4; ++dt) partO[base + dt * 16 + l15] = f2bf(o[dt][r]);
    }
    if (lg == 0) partML[sx * 65536 + bh * 2048 + qw + l15] = make_float2(mrun, lrun);
  }
}

// ---------------- combine the two s-halves -> ctx bf16 ----------------------
__global__ __launch_bounds__(256) void attn_combine(
    const unsigned short* __restrict__ partO, const float2* __restrict__ partML,
    unsigned short* __restrict__ ctx) {
  const int id = blockIdx.x * 256 + threadIdx.x;
  const int R = id >> 3;
  const int d8 = (id & 7) << 3;
  const float2 ml0 = partML[R];
  const float2 ml1 = partML[65536 + R];
  const float M = fmaxf(ml0.x, ml1.x);
  const float w0 = exp2f(ml0.x - M), w1 = exp2f(ml1.x - M);
  const float inv = __builtin_amdgcn_rcpf(ml0.y * w0 + ml1.y * w1);
  const short8 a = *reinterpret_cast<const short8*>(partO + ((size_t)R * 64 + d8));
  const short8 c = *reinterpret_cast<const short8*>(partO + ((size_t)(65536 + R) * 64 + d8));
  const int bh = R >> 11, t = R & 2047;
  const int b = bh >> 4, h = bh & 15;
  short8 outv;
#pragma unroll
  for (int e = 0; e < 8; ++e)
    outv[e] = (short)f2bf((bf2f((unsigned short)a[e]) * w0 +
                           bf2f((unsigned short)c[e]) * w1) * inv);
  *reinterpret_cast<short8*>(ctx + ((size_t)(b * 2048 + t) * 1024 + h * 64 + d8)) = outv;
}

// ---------------- launch ----------------------------------------------------
extern "C" void kernel_launch(void* const* d_in, const int* in_sizes, int n_in,
                              void* d_out, int out_size, void* d_ws, size_t ws_size,
                              hipStream_t stream) {
  const float* x = (const float*)d_in[0];
  const float* w_qkv = (const float*)d_in[1];
  const float* w_out = (const float*)d_in[2];
  // cache_k/cache_v/start_pos unused: start_pos=0, cache starts zero and is not returned.
  char* ws = (char*)d_ws;
  unsigned short* xb    = (unsigned short*)(ws);                       // 8 MiB
  unsigned short* wqkvb = (unsigned short*)(ws + (8ull  << 20));       // 6 MiB
  unsigned short* woutb = (unsigned short*)(ws + (14ull << 20));       // 2 MiB
  unsigned short* partO = (unsigned short*)(ws + (16ull << 20));       // 16 MiB
  float2* partML        = (float2*)(ws + (32ull << 20));               // 1 MiB
  unsigned short* q_buf = (unsigned short*)(ws + (40ull << 20));       // 8 MiB
  unsigned short* k_buf = (unsigned short*)(ws + (48ull << 20));       // 8 MiB
  unsigned short* vt    = (unsigned short*)(ws + (56ull << 20));       // 8 MiB
  unsigned short* ctxb  = (unsigned short*)(ws + (64ull << 20));       // 8 MiB (total 72)

  cast3<<<8192, 256, 0, stream>>>(x, xb, 1048576, w_qkv, wqkvb, 786432,
                                  w_out, woutb, 262144);
  gemm_qkv<<<dim3(32, 24), 256, 0, stream>>>(xb, wqkvb, q_buf, k_buf, vt);
  attn_kernel<<<dim3(32, 32), 256, 0, stream>>>(q_buf, k_buf, vt, partO, partML);
  attn_combine<<<2048, 256, 0, stream>>>(partO, partML, ctxb);
  gemm_nt_f32<<<dim3(32, 8), 256, 0, stream>>>(ctxb, woutb, (float*)d_out, 4096, 1024, 1024);
}

// Round 9
// 117.030 us; speedup vs baseline: 1.8688x; 1.1577x over previous
//
#include <hip/hip_runtime.h>
#include <hip/hip_bf16.h>
#include <stdint.h>

typedef __attribute__((ext_vector_type(8))) short short8;
typedef __attribute__((ext_vector_type(4))) float f32x4;

static __device__ __forceinline__ unsigned short f2bf(float f) {
  union { float f; unsigned u; } v; v.f = f;
  return (unsigned short)((v.u + 0x7fffu + ((v.u >> 16) & 1u)) >> 16);
}
static __device__ __forceinline__ float bf2f(unsigned short h) {
  union { unsigned u; float f; } v; v.u = ((unsigned)h) << 16;
  return v.f;
}
// packed f32x2 -> bf16x2 (RNE), gfx950 (no builtin; T12 recipe)
static __device__ __forceinline__ unsigned cvt_pk_bf16(float lo, float hi) {
  unsigned r;
  asm("v_cvt_pk_bf16_f32 %0, %1, %2" : "=v"(r) : "v"(lo), "v"(hi));
  return r;
}

// async global->LDS, 16B per lane (guide §5; LDS dest = wave-uniform base + lane*16)
#define GLL16(gp, lp) __builtin_amdgcn_global_load_lds(                        \
    (__attribute__((address_space(1))) void*)(uintptr_t)(gp),                  \
    (__attribute__((address_space(3))) void*)(lp), 16, 0, 0)

// element-index XOR swizzle for 64-elem (128B) bf16 rows: spreads the
// 128B-stride column reads across 8 bank-granules (T2; involution).
#define SWZ(r, e) ((e) ^ (((r) & 7) << 3))

// ---------------- fused cast f32 -> bf16 for x, w_qkv, w_out ----------------
__global__ void cast3(const float* __restrict__ a, unsigned short* __restrict__ oa, int na4,
                      const float* __restrict__ b, unsigned short* __restrict__ ob, int nb4,
                      const float* __restrict__ c, unsigned short* __restrict__ oc, int nc4) {
  int i = blockIdx.x * 256 + threadIdx.x;
  const float* src;
  unsigned short* dst;
  int j = i;
  if (j < na4) { src = a; dst = oa; }
  else if ((j -= na4) < nb4) { src = b; dst = ob; }
  else { j -= nb4; if (j >= nc4) return; src = c; dst = oc; }
  const float4 v = reinterpret_cast<const float4*>(src)[j];
  ushort4 o;
  o.x = f2bf(v.x); o.y = f2bf(v.y); o.z = f2bf(v.z); o.w = f2bf(v.w);
  reinterpret_cast<ushort4*>(dst)[j] = o;
}

// ---------------- GEMM1 + fused RoPE/layout epilogue (LDS-staged) -----------
// K-loop: T3-minimum 2-phase dbuf (issue next-tile gll16 BEFORE compute, one
// barrier/K-step — the attn loop shape; barrier's implicit vmcnt(0) is the
// drain, hidden under this tile's MFMA). Buffers: As 0/4096, Bs 8192/12288
// (ushort units); epilogue staging reuses the same 34.8KB union.
// Epilogue (unchanged from R8): q/k RoPE + [t][c] stage; v [c][t] swizzled.
__global__ __launch_bounds__(256) void gemm_qkv(
    const unsigned short* __restrict__ A, const unsigned short* __restrict__ B,
    unsigned short* __restrict__ qb, unsigned short* __restrict__ kb,
    unsigned short* __restrict__ vt) {
  constexpr int K = 1024;
  __shared__ unsigned short smem[128 * 136];  // K-loop: 32KB dbuf; epilogue: 34KB stage
  const int tid = threadIdx.x;
  const int lane = tid & 63;
  const int w = tid >> 6;
  const int wr = w >> 1, wc = w & 1;
  const int l15 = lane & 15, lg = lane >> 4;
  const size_t bm = (size_t)blockIdx.x * 128;
  const size_t bn = (size_t)blockIdx.y * 128;
  const unsigned short* Ab = A + bm * K;
  const unsigned short* Bb = B + bn * K;
  f32x4 acc[4][4];
#pragma unroll
  for (int m = 0; m < 4; ++m)
#pragma unroll
    for (int n = 0; n < 4; ++n) acc[m][n] = (f32x4){0.f, 0.f, 0.f, 0.f};

  // prologue: stage k0=0 into buf 0
#pragma unroll
  for (int p = 0; p < 2; ++p) {
    const int flat = p * 256 + tid;
    const int row = flat >> 2;
    const int c8 = (flat & 3) << 3;
    GLL16(Ab + (size_t)row * K + c8, smem + flat * 8);
    GLL16(Bb + (size_t)row * K + c8, smem + 8192 + flat * 8);
  }
  __syncthreads();
  int cur = 0;
  for (int k0 = 0; k0 < K; k0 += 32) {
    if (k0 + 32 < K) {  // issue next tile BEFORE compute (latency hides)
      const int nb = cur ^ 1;
#pragma unroll
      for (int p = 0; p < 2; ++p) {
        const int flat = p * 256 + tid;
        const int row = flat >> 2;
        const int c8 = (flat & 3) << 3;
        GLL16(Ab + (size_t)row * K + k0 + 32 + c8, smem + nb * 4096 + flat * 8);
        GLL16(Bb + (size_t)row * K + k0 + 32 + c8, smem + 8192 + nb * 4096 + flat * 8);
      }
    }
    const unsigned short* Asc = smem + cur * 4096;
    const unsigned short* Bsc = smem + 8192 + cur * 4096;
    short8 af[4], bf[4];
#pragma unroll
    for (int m = 0; m < 4; ++m)
      af[m] = *reinterpret_cast<const short8*>(Asc + ((wr * 64 + m * 16 + l15) * 32 + lg * 8));
#pragma unroll
    for (int n = 0; n < 4; ++n)
      bf[n] = *reinterpret_cast<const short8*>(Bsc + ((wc * 64 + n * 16 + l15) * 32 + lg * 8));
#pragma unroll
    for (int m = 0; m < 4; ++m)
#pragma unroll
      for (int n = 0; n < 4; ++n)
        acc[m][n] = __builtin_amdgcn_mfma_f32_16x16x32_bf16(af[m], bf[n], acc[m][n], 0, 0, 0);
    __syncthreads();  // vmcnt(0): next tile staged; lgkm: buf[cur] reads done
    cur ^= 1;
  }

  // smem is now the staging tile (final barrier above covers the handoff)
  const int sec = (int)(bn >> 10);                 // 0=q 1=k 2=v (block-uniform)
  const int hbase = (int)((bn & 1023) >> 6);
  if (sec < 2) {
    // ---- q/k: RoPE in regs, stage [t][c] as packed dwords ----
    unsigned* st32 = reinterpret_cast<unsigned*>(smem);
    const float scl = sec ? 1.0f : (0.125f * 1.44269504089f);  // q: 1/sqrt(D)*log2e
    const bool even = (l15 & 1) == 0;
#pragma unroll
    for (int n = 0; n < 4; ++n) {
      const int c = wc * 64 + n * 16 + l15;        // local col 0..127
      const int jj = (c & 63) >> 1;
      const int h = hbase + (c >> 6);
      const float freq = __expf(-(float)jj * (9.210340371976184f / 32.0f));  // ln(1e4)/32
      float sn, cs;
      __sincosf((float)h * freq, &sn, &cs);
#pragma unroll
      for (int m = 0; m < 4; ++m)
#pragma unroll
        for (int r = 0; r < 4; ++r) {
          const float v = acc[m][n][r];
          const float p = __shfl_xor(v, 1);        // partner of the RoPE pair
          if (even) {                              // even lane emits both outputs
            const float o0 = (v * cs - p * sn) * scl;
            const float o1 = (v * sn + p * cs) * scl;
            const int tl = wr * 64 + lg * 4 + m * 16 + r;
            st32[tl * 68 + (c >> 1)] = cvt_pk_bf16(o0, o1);
          }
        }
    }
    __syncthreads();
    unsigned short* dst = sec ? kb : qb;
#pragma unroll
    for (int p8 = 0; p8 < 8; ++p8) {
      const int id = p8 * 256 + tid;               // 2048 ushort8-chunks
      const int tlc = id >> 4, cch = id & 15;
      const short8 val = *reinterpret_cast<const short8*>(smem + tlc * 136 + cch * 8);
      const int trow = (int)bm + tlc;
      const int b = trow >> 11, t = trow & 2047;
      const int h = hbase + (cch >> 3), d0 = (cch & 7) * 8;
      *reinterpret_cast<short8*>(dst + (((size_t)(b * 16 + h) * 2048 + t) << 6) + d0) = val;
    }
  } else {
    // ---- v: stage [c][t] with 4-elem-granule swizzle, coalesced d-major out ----
#pragma unroll
    for (int n = 0; n < 4; ++n) {
      const int c = wc * 64 + n * 16 + l15;
      const int x = (c & 7) << 2;
#pragma unroll
      for (int m = 0; m < 4; ++m) {
        const int gt = wr * 16 + lg + m * 4;       // t-granule index (4 t each)
        ushort4 pk;
        pk.x = f2bf(acc[m][n][0]); pk.y = f2bf(acc[m][n][1]);
        pk.z = f2bf(acc[m][n][2]); pk.w = f2bf(acc[m][n][3]);
        *reinterpret_cast<ushort4*>(smem + c * 136 + ((gt ^ x) << 2)) = pk;
      }
    }
    __syncthreads();
#pragma unroll
    for (int p8 = 0; p8 < 8; ++p8) {
      const int id = p8 * 256 + tid;
      const int cl = id >> 4, tch = id & 15;
      const int x = (cl & 7) << 2;
      const short8 val =
          *reinterpret_cast<const short8*>(smem + cl * 136 + (((tch * 2) ^ x) << 2));
      const int col = (int)(bn & 1023) + cl;
      const int h = col >> 6, d = col & 63;
      const int trow = (int)bm + tch * 8;
      const int b = trow >> 11, t = trow & 2047;
      *reinterpret_cast<short8*>(vt + ((size_t)((b * 16 + h) * 64 + d)) * 2048 + t) = val;
    }
  }
}

// ---------------- NT GEMM (output fp32): C = ctx @ w_out^T ------------------
// Same T3-minimum 2-phase dbuf K-loop.
__global__ __launch_bounds__(256) void gemm_nt_f32(
    const unsigned short* __restrict__ A, const unsigned short* __restrict__ B,
    float* __restrict__ Cout, int M, int N, int K) {
  __shared__ unsigned short smem[4 * 4096];  // As 0/4096, Bs 8192/12288
  const int tid = threadIdx.x;
  const int lane = tid & 63;
  const int w = tid >> 6;
  const int wr = w >> 1, wc = w & 1;
  const int l15 = lane & 15, lg = lane >> 4;
  const size_t bm = (size_t)blockIdx.x * 128;
  const size_t bn = (size_t)blockIdx.y * 128;
  const unsigned short* Ab = A + bm * K;
  const unsigned short* Bb = B + bn * K;
  f32x4 acc[4][4];
#pragma unroll
  for (int m = 0; m < 4; ++m)
#pragma unroll
    for (int n = 0; n < 4; ++n) acc[m][n] = (f32x4){0.f, 0.f, 0.f, 0.f};

#pragma unroll
  for (int p = 0; p < 2; ++p) {
    const int flat = p * 256 + tid;
    const int row = flat >> 2;
    const int c8 = (flat & 3) << 3;
    GLL16(Ab + (size_t)row * K + c8, smem + flat * 8);
    GLL16(Bb + (size_t)row * K + c8, smem + 8192 + flat * 8);
  }
  __syncthreads();
  int cur = 0;
  for (int k0 = 0; k0 < K; k0 += 32) {
    if (k0 + 32 < K) {
      const int nb = cur ^ 1;
#pragma unroll
      for (int p = 0; p < 2; ++p) {
        const int flat = p * 256 + tid;
        const int row = flat >> 2;
        const int c8 = (flat & 3) << 3;
        GLL16(Ab + (size_t)row * K + k0 + 32 + c8, smem + nb * 4096 + flat * 8);
        GLL16(Bb + (size_t)row * K + k0 + 32 + c8, smem + 8192 + nb * 4096 + flat * 8);
      }
    }
    const unsigned short* Asc = smem + cur * 4096;
    const unsigned short* Bsc = smem + 8192 + cur * 4096;
    short8 af[4], bf[4];
#pragma unroll
    for (int m = 0; m < 4; ++m)
      af[m] = *reinterpret_cast<const short8*>(Asc + ((wr * 64 + m * 16 + l15) * 32 + lg * 8));
#pragma unroll
    for (int n = 0; n < 4; ++n)
      bf[n] = *reinterpret_cast<const short8*>(Bsc + ((wc * 64 + n * 16 + l15) * 32 + lg * 8));
#pragma unroll
    for (int m = 0; m < 4; ++m)
#pragma unroll
      for (int n = 0; n < 4; ++n)
        acc[m][n] = __builtin_amdgcn_mfma_f32_16x16x32_bf16(af[m], bf[n], acc[m][n], 0, 0, 0);
    __syncthreads();
    cur ^= 1;
  }
  const size_t row0 = bm + wr * 64 + lg * 4;
  const size_t col0 = bn + wc * 64 + l15;
#pragma unroll
  for (int m = 0; m < 4; ++m)
#pragma unroll
    for (int n = 0; n < 4; ++n)
#pragma unroll
      for (int r = 0; r < 4; ++r)
        Cout[(row0 + m * 16 + r) * N + col0 + n * 16] = acc[m][n][r];
}

// ---------------- flash attention, causal, s-split x2 + partials ------------
// grid (32, B*H): px = x>>1 pairs q-tiles (px, 31-px); sx = x&1 selects the
// lower/upper half of each q-tile's s-range -> uniform ~16.5 tile-units/block.
// Emits unnormalized partials (O bf16, m/l f32); attn_combine merges.
__global__ __launch_bounds__(256) void attn_kernel(
    const unsigned short* __restrict__ qb, const unsigned short* __restrict__ kb,
    const unsigned short* __restrict__ vt, unsigned short* __restrict__ partO,
    float2* __restrict__ partML) {
  __shared__ unsigned short Ks[2][64 * 64];  // [s][d], swizzled
  __shared__ unsigned short Vs[2][64 * 64];  // [d][s], swizzled
  __shared__ unsigned short Ps[4][16 * 64];  // per-wave P [q][s], swizzled
  const int tid = threadIdx.x;
  const int lane = tid & 63;
  const int w = tid >> 6;
  const int l15 = lane & 15, lg = lane >> 4;
  const int sx = blockIdx.x & 1, px = blockIdx.x >> 1;
  const int bh = blockIdx.y;
  unsigned short* Pw = &Ps[w][0];

  const unsigned short* kg[2];
  const unsigned short* vg[2];
#pragma unroll
  for (int p = 0; p < 2; ++p) {
    const int f = p * 256 + tid;
    const int row = f >> 3;
    const int gc8 = SWZ(row, (f & 7) << 3);
    kg[p] = kb + ((size_t)bh * 2048 + row) * 64 + gc8;
    vg[p] = vt + ((size_t)bh * 64 + row) * 2048 + gc8;
  }

  int cur = 0;
#pragma unroll 1
  for (int mem = 0; mem < 2; ++mem) {
    const int qt = mem ? (31 - px) : px;
    const int nt = qt + 1;
    const int mid = (nt + 1) >> 1;
    const int sb = sx ? mid : 0;
    const int se = sx ? nt : mid;
    const int nh = se - sb;
    const int qw = qt * 64 + w * 16;
    const unsigned short* Qp = qb + ((size_t)bh * 2048 + qw) * 64;
    const short8 qf0 = *reinterpret_cast<const short8*>(Qp + (size_t)l15 * 64 + lg * 8);
    const short8 qf1 = *reinterpret_cast<const short8*>(Qp + (size_t)l15 * 64 + 32 + lg * 8);
    float mrun = -1e30f, lrun = 0.f;
    f32x4 o[4];
#pragma unroll
    for (int dt = 0; dt < 4; ++dt) o[dt] = (f32x4){0.f, 0.f, 0.f, 0.f};

    if (nh > 0) {
#pragma unroll
      for (int p = 0; p < 2; ++p) {
        const int f = p * 256 + tid;
        GLL16(kg[p] + (size_t)sb * 64 * 64, &Ks[cur][f * 8]);
        GLL16(vg[p] + (size_t)sb * 64, &Vs[cur][f * 8]);
      }
      __syncthreads();

#pragma unroll 1
      for (int it = 0; it < nh; ++it) {
        const int ti = sb + it;
        const int s0 = ti * 64;
        if (it + 1 < nh) {
#pragma unroll
          for (int p = 0; p < 2; ++p) {
            const int f = p * 256 + tid;
            GLL16(kg[p] + (size_t)(ti + 1) * 64 * 64, &Ks[cur ^ 1][f * 8]);
            GLL16(vg[p] + (size_t)(ti + 1) * 64, &Vs[cur ^ 1][f * 8]);
          }
        }
        const unsigned short* Kc = &Ks[cur][0];
        const unsigned short* Vc = &Vs[cur][0];
        f32x4 sc[4];
        __builtin_amdgcn_s_setprio(1);
#pragma unroll
        for (int st = 0; st < 4; ++st) {
          const int kr = st * 16 + l15;
          const short8 kf0 = *reinterpret_cast<const short8*>(Kc + kr * 64 + SWZ(kr, lg * 8));
          const short8 kf1 = *reinterpret_cast<const short8*>(Kc + kr * 64 + SWZ(kr, 32 + lg * 8));
          f32x4 z = (f32x4){0.f, 0.f, 0.f, 0.f};
          z = __builtin_amdgcn_mfma_f32_16x16x32_bf16(kf0, qf0, z, 0, 0, 0);
          z = __builtin_amdgcn_mfma_f32_16x16x32_bf16(kf1, qf1, z, 0, 0, 0);
          sc[st] = z;
        }
        __builtin_amdgcn_s_setprio(0);
        if (s0 + 63 > qw) {
          const int sbase = s0 + lg * 4 - qw - l15;
#pragma unroll
          for (int st = 0; st < 4; ++st)
#pragma unroll
            for (int r = 0; r < 4; ++r)
              if (sbase + st * 16 + r > 0) sc[st][r] = -1e30f;
        }
        float tmax = sc[0][0];
#pragma unroll
        for (int st = 0; st < 4; ++st)
#pragma unroll
          for (int r = 0; r < 4; ++r) tmax = fmaxf(tmax, sc[st][r]);
        tmax = fmaxf(tmax, __shfl_xor(tmax, 16));
        tmax = fmaxf(tmax, __shfl_xor(tmax, 32));
        if (__any(tmax > mrun + 8.f)) {
          const float mn = fmaxf(mrun, tmax);
          const float c = exp2f(mrun - mn);
          mrun = mn;
          lrun *= c;
#pragma unroll
          for (int r = 0; r < 4; ++r) {
            const float cq = __shfl(c, lg * 4 + r);
            o[0][r] *= cq; o[1][r] *= cq; o[2][r] *= cq; o[3][r] *= cq;
          }
        }
        float psum = 0.f;
#pragma unroll
        for (int st = 0; st < 4; ++st) {
          const float p0 = exp2f(sc[st][0] - mrun);
          const float p1 = exp2f(sc[st][1] - mrun);
          const float p2 = exp2f(sc[st][2] - mrun);
          const float p3 = exp2f(sc[st][3] - mrun);
          psum += (p0 + p1) + (p2 + p3);
          const unsigned lo = cvt_pk_bf16(p0, p1);
          const unsigned hi = cvt_pk_bf16(p2, p3);
          const int off = l15 * 64 + SWZ(l15, st * 16 + lg * 4);
          *reinterpret_cast<uint2*>(Pw + off) = make_uint2(lo, hi);
        }
        psum += __shfl_xor(psum, 16);
        psum += __shfl_xor(psum, 32);
        lrun += psum;
        __builtin_amdgcn_s_setprio(1);
#pragma unroll
        for (int sc2 = 0; sc2 < 2; ++sc2) {
          const short8 pf =
              *reinterpret_cast<const short8*>(Pw + l15 * 64 + SWZ(l15, sc2 * 32 + lg * 8));
#pragma unroll
          for (int dt = 0; dt < 4; ++dt) {
            const int vr = dt * 16 + l15;
            const short8 vf =
                *reinterpret_cast<const short8*>(Vc + vr * 64 + SWZ(vr, sc2 * 32 + lg * 8));
            o[dt] = __builtin_amdgcn_mfma_f32_16x16x32_bf16(pf, vf, o[dt], 0, 0, 0);
          }
        }
        __builtin_amdgcn_s_setprio(0);
        __syncthreads();
        cur ^= 1;
      }
    }
#pragma unroll
    for (int r = 0; r < 4; ++r) {
      const int t = qw + lg * 4 + r;
      const size_t base = ((size_t)sx * 65536 + (size_t)bh * 2048 + t) * 64;
#pragma unroll
      for (int dt = 0; dt < 4; ++dt) partO[base + dt * 16 + l15] = f2bf(o[dt][r]);
    }
    if (lg == 0) partML[sx * 65536 + bh * 2048 + qw + l15] = make_float2(mrun, lrun);
  }
}

// ---------------- combine the two s-halves -> ctx bf16 ----------------------
__global__ __launch_bounds__(256) void attn_combine(
    const unsigned short* __restrict__ partO, const float2* __restrict__ partML,
    unsigned short* __restrict__ ctx) {
  const int id = blockIdx.x * 256 + threadIdx.x;
  const int R = id >> 3;
  const int d8 = (id & 7) << 3;
  const float2 ml0 = partML[R];
  const float2 ml1 = partML[65536 + R];
  const float M = fmaxf(ml0.x, ml1.x);
  const float w0 = exp2f(ml0.x - M), w1 = exp2f(ml1.x - M);
  const float inv = __builtin_amdgcn_rcpf(ml0.y * w0 + ml1.y * w1);
  const short8 a = *reinterpret_cast<const short8*>(partO + ((size_t)R * 64 + d8));
  const short8 c = *reinterpret_cast<const short8*>(partO + ((size_t)(65536 + R) * 64 + d8));
  const int bh = R >> 11, t = R & 2047;
  const int b = bh >> 4, h = bh & 15;
  short8 outv;
#pragma unroll
  for (int e = 0; e < 8; ++e)
    outv[e] = (short)f2bf((bf2f((unsigned short)a[e]) * w0 +
                           bf2f((unsigned short)c[e]) * w1) * inv);
  *reinterpret_cast<short8*>(ctx + ((size_t)(b * 2048 + t) * 1024 + h * 64 + d8)) = outv;
}

// ---------------- launch ----------------------------------------------------
extern "C" void kernel_launch(void* const* d_in, const int* in_sizes, int n_in,
                              void* d_out, int out_size, void* d_ws, size_t ws_size,
                              hipStream_t stream) {
  const float* x = (const float*)d_in[0];
  const float* w_qkv = (const float*)d_in[1];
  const float* w_out = (const float*)d_in[2];
  // cache_k/cache_v/start_pos unused: start_pos=0, cache starts zero and is not returned.
  char* ws = (char*)d_ws;
  unsigned short* xb    = (unsigned short*)(ws);                       // 8 MiB
  unsigned short* wqkvb = (unsigned short*)(ws + (8ull  << 20));       // 6 MiB
  unsigned short* woutb = (unsigned short*)(ws + (14ull << 20));       // 2 MiB
  unsigned short* partO = (unsigned short*)(ws + (16ull << 20));       // 16 MiB
  float2* partML        = (float2*)(ws + (32ull << 20));               // 1 MiB
  unsigned short* q_buf = (unsigned short*)(ws + (40ull << 20));       // 8 MiB
  unsigned short* k_buf = (unsigned short*)(ws + (48ull << 20));       // 8 MiB
  unsigned short* vt    = (unsigned short*)(ws + (56ull << 20));       // 8 MiB
  unsigned short* ctxb  = (unsigned short*)(ws + (64ull << 20));       // 8 MiB (total 72)

  cast3<<<8192, 256, 0, stream>>>(x, xb, 1048576, w_qkv, wqkvb, 786432,
                                  w_out, woutb, 262144);
  gemm_qkv<<<dim3(32, 24), 256, 0, stream>>>(xb, wqkvb, q_buf, k_buf, vt);
  attn_kernel<<<dim3(32, 32), 256, 0, stream>>>(q_buf, k_buf, vt, partO, partML);
  attn_combine<<<2048, 256, 0, stream>>>(partO, partML, ctxb);
  gemm_nt_f32<<<dim3(32, 8), 256, 0, stream>>>(ctxb, woutb, (float*)d_out, 4096, 1024, 1024);
}